// Round 8
// baseline (265.015 us; speedup 1.0000x reference)
//
#include <hip/hip_runtime.h>
#include <hip/hip_bf16.h>

#define S_STEPS 64

typedef __bf16 bf16x8 __attribute__((ext_vector_type(8)));
typedef float  f32x4  __attribute__((ext_vector_type(4)));
typedef int    i32x4  __attribute__((ext_vector_type(4)));

// ---- async 16B global->LDS (wave-uniform base + lane*16 contiguous dest) ----
__device__ __forceinline__ void async16(const void* g, void* l) {
    __builtin_amdgcn_global_load_lds((const __attribute__((address_space(1))) void*)g,
                                     (__attribute__((address_space(3))) void*)l,
                                     16, 0, 0);
}

// =============== merged prep: encoder + W0 bf16x3 split + W1/W2 i8 quant ===============
// grid: [0,512) encoder (bx=bid&1, by=bid>>1) | [512,1024) W0 split | [1024,2560) quant
__global__ void snn_prep(const float4* __restrict__ xv, ushort4* __restrict__ r,
                         const float4* __restrict__ W0, ushort4* __restrict__ w0out,
                         const float4* __restrict__ W1, const float4* __restrict__ W2,
                         char4* __restrict__ w1out, char4* __restrict__ w2out) {
    constexpr int T = 128, F4 = 128;          // F/4
    constexpr int NB_ENC = 512;               // (F4/64)*B
    constexpr int N0_4 = 1024 * 512 / 4;      // 131072
    constexpr int NB_W0 = N0_4 / 256;         // 512
    constexpr int N1_4 = 1024 * 1024 / 4;     // 262144
    constexpr int N2_4 = 512 * 1024 / 4;      // 131072
    __shared__ int4 red[4][64];

    const int bid = blockIdx.x;
    if (bid < NB_ENC) {
        // ---------------- delta encoder (T-parallel) ----------------
        const int f4i = threadIdx.x & 63;
        const int tc  = threadIdx.x >> 6;     // 0..3
        const int b   = bid >> 1;
        const int f4  = (bid & 1) * 64 + f4i;
        int c0 = 0, c1 = 0, c2 = 0, c3 = 0;
        if (b > 0) {
            const float4* xb = xv + ((size_t)b * T + tc * 32) * F4 + f4;
            const float4* xp = xb - (size_t)T * F4;
            for (int t = 0; t < 32; ++t) {
                float4 a = xb[(size_t)t * F4];
                float4 p = xp[(size_t)t * F4];
                c0 += (__fsub_rn(a.x, p.x) >= 0.2f) ? 1 : 0;
                c1 += (__fsub_rn(a.y, p.y) >= 0.2f) ? 1 : 0;
                c2 += (__fsub_rn(a.z, p.z) >= 0.2f) ? 1 : 0;
                c3 += (__fsub_rn(a.w, p.w) >= 0.2f) ? 1 : 0;
            }
        }
        red[tc][f4i] = int4{c0, c1, c2, c3};
        __syncthreads();
        if (tc == 0) {
            int4 a = red[0][f4i], bb = red[1][f4i], cc = red[2][f4i], dd = red[3][f4i];
            int s0 = a.x + bb.x + cc.x + dd.x;
            int s1 = a.y + bb.y + cc.y + dd.y;
            int s2 = a.z + bb.z + cc.z + dd.z;
            int s3 = a.w + bb.w + cc.w + dd.w;
            ushort4 o;
            o.x = __hip_bfloat16_raw(__float2bfloat16((float)s0 * (1.0f / 128.0f))).x;
            o.y = __hip_bfloat16_raw(__float2bfloat16((float)s1 * (1.0f / 128.0f))).x;
            o.z = __hip_bfloat16_raw(__float2bfloat16((float)s2 * (1.0f / 128.0f))).x;
            o.w = __hip_bfloat16_raw(__float2bfloat16((float)s3 * (1.0f / 128.0f))).x;
            r[(size_t)b * F4 + f4] = o;
        }
    } else if (bid < NB_ENC + NB_W0) {
        // ---------------- W0 -> bf16 hi/mid/lo (exact 3-way split) ----------------
        int j = (bid - NB_ENC) * 256 + threadIdx.x;
        float4 w = W0[j];
        float wv[4] = {w.x, w.y, w.z, w.w};
        unsigned short hv[4], mv[4], lv[4];
        #pragma unroll
        for (int q = 0; q < 4; ++q) {
            __hip_bfloat16 hh = __float2bfloat16(wv[q]);
            float r1 = __fsub_rn(wv[q], __bfloat162float(hh));   // exact
            __hip_bfloat16 mm = __float2bfloat16(r1);
            float r2 = __fsub_rn(r1, __bfloat162float(mm));      // exact
            hv[q] = __hip_bfloat16_raw(hh).x;
            mv[q] = __hip_bfloat16_raw(mm).x;
            lv[q] = __hip_bfloat16_raw(__float2bfloat16(r2)).x;
        }
        w0out[j]             = ushort4{hv[0], hv[1], hv[2], hv[3]};
        w0out[j + N0_4]      = ushort4{mv[0], mv[1], mv[2], mv[3]};
        w0out[j + 2 * N0_4]  = ushort4{lv[0], lv[1], lv[2], lv[3]};
    } else {
        // ---------------- W1/W2 -> i8 fixed-point digits [d2][d1][d0] ----------------
        // e = rint(w*2^27), |e| <= 2^22; e = d0 + 256*d1 + 65536*d2 (exact).
        int i = (bid - NB_ENC - NB_W0) * 256 + threadIdx.x;
        const float4* W; char4* out; int n4; int j = i;
        if (j < N1_4) { W = W1; out = w1out; n4 = N1_4; }
        else { j -= N1_4; W = W2; out = w2out; n4 = N2_4; }
        float4 w = W[j];
        float wv[4] = {w.x, w.y, w.z, w.w};
        signed char d2v[4], d1v[4], d0v[4];
        #pragma unroll
        for (int q = 0; q < 4; ++q) {
            int e  = __float2int_rn(wv[q] * 134217728.0f);       // w * 2^27
            int d0 = (int)(signed char)(e & 0xff);
            int e1 = (e - d0) >> 8;                              // exact
            int d1 = (int)(signed char)(e1 & 0xff);
            int d2 = (e1 - d1) >> 8;                             // exact, in [-64,64]
            d0v[q] = (signed char)d0;
            d1v[q] = (signed char)d1;
            d2v[q] = (signed char)d2;
        }
        out[j]          = make_char4(d2v[0], d2v[1], d2v[2], d2v[3]);
        out[j + n4]     = make_char4(d1v[0], d1v[1], d1v[2], d1v[3]);
        out[j + 2 * n4] = make_char4(d0v[0], d0v[1], d0v[2], d0v[3]);
    }
}

// Swizzled staging map (per 16-row x 64-byte group = 64 slots x 16B):
//   slot s holds global (row = s>>2, chunk16B = ((s&3)+(s>>2)+(s>>4)) & 3)
//   frag read slot(rho,kap) = 4*rho + ((kap - rho - (rho>>2)) & 3)
//
// B-MAJOR M-LAYOUT: GEMM M-row index = b*64 + s; wave's 64-row tile = one batch
// element, LIF scan fused in the epilogue (s = 4*seg + r, seg = i*4 + kap).
//
// TRIPLE-BUFFERED, ONE BARRIER PER TILE, FULLY UNROLLED (constexpr shapes):
// all buffer selectors / staging (part,kt) / fold points are compile-time.

// ================= i8 GEMM A + fused LIF: block 128x256, wave 64x128 =================
// M=16384, N=1024, K=1024 hard-coded.
__global__ __launch_bounds__(256, 2)
void snn_gemm_i8_w_lif(const signed char* __restrict__ A,
                       const signed char* __restrict__ Wq,
                       const float* __restrict__ bias,
                       signed char* __restrict__ Sout) {   // spikes i8, rows b*64+s
    constexpr int N = 1024, K = 1024, KT = K >> 6, NT = 3 * KT;   // 16, 48
    constexpr size_t PK = (size_t)N * K;
    __shared__ __align__(16) char As[3 * 8192];    // 3 x 8 groups x 1024B
    __shared__ __align__(16) char Bs[3 * 16384];   // 3 x 16 groups x 1024B
    const int t    = threadIdx.x;
    const int wave = t >> 6;
    const int lane = t & 63;

    int m_idx, n_idx;
    {
        int gx = gridDim.x, gy = gridDim.y;
        int flat = blockIdx.y * gx + blockIdx.x;
        if ((gy & 7) == 0) {
            int x = flat & 7, local = flat >> 3, h = gy >> 3;
            m_idx = x * h + (local % h);
            n_idx = local / h;
        } else { m_idx = blockIdx.y; n_idx = blockIdx.x; }
    }
    const int m0 = m_idx * 128;
    const int n0 = n_idx * 256;
    const int wm = (wave >> 1) * 64;
    const int wn = (wave & 1) * 128;

    const int srow = lane >> 2;
    const int schk = ((lane & 3) + (lane >> 2) + (lane >> 4)) & 3;
    const int rho  = lane & 15;
    const int kap  = lane >> 4;
    const int foff = ((rho << 2) + ((kap - rho - (rho >> 2)) & 3)) * 16;   // bytes

    size_t aOff[2], bOff[4];
    #pragma unroll
    for (int q = 0; q < 2; ++q)
        aOff[q] = (size_t)(m0 + (wave * 2 + q) * 16 + srow) * K + schk * 16;
    #pragma unroll
    for (int q = 0; q < 4; ++q)
        bOff[q] = (size_t)(n0 + (wave * 4 + q) * 16 + srow) * K + schk * 16;

    i32x4 acc[4][8] = {};
    i32x4 af[2][4], bLo[4], bHi[4];

    auto stageT = [&](int p, int kt, int bsel) {
        const int kk = kt << 6;
        char* as = As + bsel * 8192;
        char* bs = Bs + bsel * 16384;
        #pragma unroll
        for (int q = 0; q < 2; ++q)
            async16(A + aOff[q] + kk, as + (wave * 2 + q) * 1024 + lane * 16);
        const signed char* Bw = Wq + (size_t)p * PK;
        #pragma unroll
        for (int q = 0; q < 4; ++q)
            async16(Bw + bOff[q] + kk, bs + (wave * 4 + q) * 1024 + lane * 16);
    };

    // prologue: stage tiles 0,1; read tile 0; lo-half of tile 0
    stageT(0, 0, 0);
    stageT(0, 1, 1);
    asm volatile("s_waitcnt vmcnt(6)" ::: "memory");
    __builtin_amdgcn_s_barrier();
    #pragma unroll
    for (int q = 0; q < 4; ++q)
        af[0][q] = *(const i32x4*)&As[((wm >> 4) + q) * 1024 + foff];
    #pragma unroll
    for (int q = 0; q < 4; ++q) {
        bLo[q] = *(const i32x4*)&Bs[((wn >> 4) + q) * 1024 + foff];
        bHi[q] = *(const i32x4*)&Bs[((wn >> 4) + 4 + q) * 1024 + foff];
    }
    asm volatile("s_waitcnt lgkmcnt(0)" ::: "memory");
    __builtin_amdgcn_sched_barrier(0);
    #pragma unroll
    for (int q = 0; q < 4; ++q)
        #pragma unroll
        for (int j = 0; j < 4; ++j)
            acc[q][j] = __builtin_amdgcn_mfma_i32_16x16x64_i8(af[0][q], bLo[j], acc[q][j], 0, 0, 0);

    // fully unrolled pipeline: iteration i = hi-half(i) + read(i+1) + lo-half(i+1)
    #pragma unroll
    for (int i = 0; i < NT - 1; ++i) {
        const int nt = i + 2;                  // tile to stage (constant under unroll)
        if (nt < NT) {
            stageT(nt / KT, nt % KT, nt % 3);
            asm volatile("s_waitcnt vmcnt(6)" ::: "memory");   // tile i+1 landed
        } else {
            asm volatile("s_waitcnt vmcnt(0)" ::: "memory");
        }
        __builtin_amdgcn_s_barrier();                          // tile i+1 visible
        const char* as = As + ((i + 1) % 3) * 8192;
        const char* bs = Bs + ((i + 1) % 3) * 16384;
        #pragma unroll
        for (int q = 0; q < 4; ++q)
            af[(i + 1) & 1][q] = *(const i32x4*)&as[((wm >> 4) + q) * 1024 + foff];
        #pragma unroll
        for (int q = 0; q < 4; ++q)
            bLo[q] = *(const i32x4*)&bs[((wn >> 4) + q) * 1024 + foff];
        __builtin_amdgcn_sched_barrier(0);                     // reads issued first
        #pragma unroll
        for (int q = 0; q < 4; ++q)
            #pragma unroll
            for (int j = 0; j < 4; ++j)
                acc[q][4 + j] = __builtin_amdgcn_mfma_i32_16x16x64_i8(af[i & 1][q], bHi[j], acc[q][4 + j], 0, 0, 0);
        #pragma unroll
        for (int q = 0; q < 4; ++q)
            bHi[q] = *(const i32x4*)&bs[((wn >> 4) + 4 + q) * 1024 + foff];
        asm volatile("s_waitcnt lgkmcnt(0)" ::: "memory");     // frags of i+1 in regs
        __builtin_amdgcn_sched_barrier(0);
        if (((i + 1) % KT) == 0) {                             // Horner fold (static)
            #pragma unroll
            for (int q = 0; q < 4; ++q)
                #pragma unroll
                for (int j = 0; j < 8; ++j)
                    acc[q][j] = acc[q][j] * 256;
        }
        #pragma unroll
        for (int q = 0; q < 4; ++q)
            #pragma unroll
            for (int j = 0; j < 4; ++j)
                acc[q][j] = __builtin_amdgcn_mfma_i32_16x16x64_i8(af[(i + 1) & 1][q], bLo[j], acc[q][j], 0, 0, 0);
    }
    // final hi-half of tile NT-1
    #pragma unroll
    for (int q = 0; q < 4; ++q)
        #pragma unroll
        for (int j = 0; j < 4; ++j)
            acc[q][4 + j] = __builtin_amdgcn_mfma_i32_16x16x64_i8(af[(NT - 1) & 1][q], bHi[j], acc[q][4 + j], 0, 0, 0);

    // ---------- fused LIF epilogue ----------
    const float SCALE = 7.450580596923828e-9f;   // 2^-27
    float bb[8];
    #pragma unroll
    for (int j = 0; j < 8; ++j)
        bb[j] = bias[n0 + wn + j * 16 + (lane & 15)];
    #pragma unroll
    for (int i = 0; i < 4; ++i)
        #pragma unroll
        for (int j = 0; j < 8; ++j) {
            i32x4 v = acc[i][j];
            f32x4 c;
            #pragma unroll
            for (int r = 0; r < 4; ++r)
                c[r] = (float)v[r] * SCALE + bb[j];
            acc[i][j] = __builtin_bit_cast(i32x4, c);
        }
    float mj[8] = {0.f, 0.f, 0.f, 0.f, 0.f, 0.f, 0.f, 0.f};
    signed char* So = Sout + (size_t)(m0 + wm) * N;   // rows b*64 + s
    #pragma unroll
    for (int seg = 0; seg < 16; ++seg) {
        const int si = seg >> 2, sk = seg & 3;
        const int src = (lane & 15) | (((sk + 3) & 3) << 4);
        #pragma unroll
        for (int j = 0; j < 8; ++j) {
            float tin = __shfl(mj[j], src);
            if (seg > 0 && kap == sk) mj[j] = tin;
        }
        if (kap == sk) {
            #pragma unroll
            for (int j = 0; j < 8; ++j) {
                f32x4 c = __builtin_bit_cast(f32x4, acc[si][j]);
                const int ng = n0 + wn + j * 16 + (lane & 15);
                #pragma unroll
                for (int r = 0; r < 4; ++r) {
                    float rst = (mj[j] > 1.0f) ? 1.0f : 0.0f;
                    mj[j] = __fsub_rn(__fadd_rn(__fmul_rn(0.9f, mj[j]), c[r]), rst);
                    So[(size_t)(seg * 4 + r) * N + ng] = (mj[j] > 1.0f) ? (signed char)1 : (signed char)0;
                }
            }
        }
    }
}

// ================= i8 GEMM B + fused LIF -> f32 output: block 128x128, wave 64x64 =====
// M=16384, N=512, K=1024 hard-coded.
__global__ __launch_bounds__(256, 2)
void snn_gemm_i8_n_lif(const signed char* __restrict__ A,
                       const signed char* __restrict__ Wq,
                       const float* __restrict__ bias,
                       float* __restrict__ Dout) {      // [S, B, N] f32 spikes
    constexpr int N = 512, K = 1024, KT = K >> 6, NT = 3 * KT;   // 16, 48
    constexpr int BSZ = 256;
    constexpr size_t PK = (size_t)N * K;
    __shared__ __align__(16) char As[3 * 8192];
    __shared__ __align__(16) char Bs[3 * 8192];
    const int t    = threadIdx.x;
    const int wave = t >> 6;
    const int lane = t & 63;

    int m_idx, n_idx;
    {
        int gx = gridDim.x, gy = gridDim.y;
        int flat = blockIdx.y * gx + blockIdx.x;
        if ((gy & 7) == 0) {
            int x = flat & 7, local = flat >> 3, h = gy >> 3;
            m_idx = x * h + (local % h);
            n_idx = local / h;
        } else { m_idx = blockIdx.y; n_idx = blockIdx.x; }
    }
    const int m0 = m_idx * 128;
    const int n0 = n_idx * 128;
    const int wm = (wave & 1) * 64;
    const int wn = (wave >> 1) * 64;

    const int srow = lane >> 2;
    const int schk = ((lane & 3) + (lane >> 2) + (lane >> 4)) & 3;
    const int rho  = lane & 15;
    const int kap  = lane >> 4;
    const int foff = ((rho << 2) + ((kap - rho - (rho >> 2)) & 3)) * 16;   // bytes

    size_t aOff[2], bOff[2];
    #pragma unroll
    for (int q = 0; q < 2; ++q) {
        aOff[q] = (size_t)(m0 + (wave * 2 + q) * 16 + srow) * K + schk * 16;
        bOff[q] = (size_t)(n0 + (wave * 2 + q) * 16 + srow) * K + schk * 16;
    }

    i32x4 acc[4][4] = {};
    i32x4 af[2][4], bLo[2], bHi[2];

    auto stageT = [&](int p, int kt, int bsel) {
        const int kk = kt << 6;
        char* as = As + bsel * 8192;
        char* bs = Bs + bsel * 8192;
        const signed char* Bw = Wq + (size_t)p * PK;
        #pragma unroll
        for (int q = 0; q < 2; ++q) {
            async16(A  + aOff[q] + kk, as + (wave * 2 + q) * 1024 + lane * 16);
            async16(Bw + bOff[q] + kk, bs + (wave * 2 + q) * 1024 + lane * 16);
        }
    };

    stageT(0, 0, 0);
    stageT(0, 1, 1);
    asm volatile("s_waitcnt vmcnt(4)" ::: "memory");
    __builtin_amdgcn_s_barrier();
    #pragma unroll
    for (int q = 0; q < 4; ++q)
        af[0][q] = *(const i32x4*)&As[((wm >> 4) + q) * 1024 + foff];
    #pragma unroll
    for (int q = 0; q < 2; ++q) {
        bLo[q] = *(const i32x4*)&Bs[((wn >> 4) + q) * 1024 + foff];
        bHi[q] = *(const i32x4*)&Bs[((wn >> 4) + 2 + q) * 1024 + foff];
    }
    asm volatile("s_waitcnt lgkmcnt(0)" ::: "memory");
    __builtin_amdgcn_sched_barrier(0);
    #pragma unroll
    for (int q = 0; q < 4; ++q)
        #pragma unroll
        for (int j = 0; j < 2; ++j)
            acc[q][j] = __builtin_amdgcn_mfma_i32_16x16x64_i8(af[0][q], bLo[j], acc[q][j], 0, 0, 0);

    #pragma unroll
    for (int i = 0; i < NT - 1; ++i) {
        const int nt = i + 2;
        if (nt < NT) {
            stageT(nt / KT, nt % KT, nt % 3);
            asm volatile("s_waitcnt vmcnt(4)" ::: "memory");
        } else {
            asm volatile("s_waitcnt vmcnt(0)" ::: "memory");
        }
        __builtin_amdgcn_s_barrier();
        const char* as = As + ((i + 1) % 3) * 8192;
        const char* bs = Bs + ((i + 1) % 3) * 8192;
        #pragma unroll
        for (int q = 0; q < 4; ++q)
            af[(i + 1) & 1][q] = *(const i32x4*)&as[((wm >> 4) + q) * 1024 + foff];
        #pragma unroll
        for (int q = 0; q < 2; ++q)
            bLo[q] = *(const i32x4*)&bs[((wn >> 4) + q) * 1024 + foff];
        __builtin_amdgcn_sched_barrier(0);
        #pragma unroll
        for (int q = 0; q < 4; ++q)
            #pragma unroll
            for (int j = 0; j < 2; ++j)
                acc[q][2 + j] = __builtin_amdgcn_mfma_i32_16x16x64_i8(af[i & 1][q], bHi[j], acc[q][2 + j], 0, 0, 0);
        #pragma unroll
        for (int q = 0; q < 2; ++q)
            bHi[q] = *(const i32x4*)&bs[((wn >> 4) + 2 + q) * 1024 + foff];
        asm volatile("s_waitcnt lgkmcnt(0)" ::: "memory");
        __builtin_amdgcn_sched_barrier(0);
        if (((i + 1) % KT) == 0) {
            #pragma unroll
            for (int q = 0; q < 4; ++q)
                #pragma unroll
                for (int j = 0; j < 4; ++j)
                    acc[q][j] = acc[q][j] * 256;
        }
        #pragma unroll
        for (int q = 0; q < 4; ++q)
            #pragma unroll
            for (int j = 0; j < 2; ++j)
                acc[q][j] = __builtin_amdgcn_mfma_i32_16x16x64_i8(af[(i + 1) & 1][q], bLo[j], acc[q][j], 0, 0, 0);
    }
    #pragma unroll
    for (int q = 0; q < 4; ++q)
        #pragma unroll
        for (int j = 0; j < 2; ++j)
            acc[q][2 + j] = __builtin_amdgcn_mfma_i32_16x16x64_i8(af[(NT - 1) & 1][q], bHi[j], acc[q][2 + j], 0, 0, 0);

    // ---------- fused LIF epilogue -> f32 spikes [S, B, N] ----------
    const float SCALE = 7.450580596923828e-9f;   // 2^-27
    float bb[4];
    #pragma unroll
    for (int j = 0; j < 4; ++j)
        bb[j] = bias[n0 + wn + j * 16 + (lane & 15)];
    #pragma unroll
    for (int i = 0; i < 4; ++i)
        #pragma unroll
        for (int j = 0; j < 4; ++j) {
            i32x4 v = acc[i][j];
            f32x4 c;
            #pragma unroll
            for (int r = 0; r < 4; ++r)
                c[r] = (float)v[r] * SCALE + bb[j];
            acc[i][j] = __builtin_bit_cast(i32x4, c);
        }
    float mj[4] = {0.f, 0.f, 0.f, 0.f};
    const int b_idx = (m0 + wm) >> 6;
    #pragma unroll
    for (int seg = 0; seg < 16; ++seg) {
        const int si = seg >> 2, sk = seg & 3;
        const int src = (lane & 15) | (((sk + 3) & 3) << 4);
        #pragma unroll
        for (int j = 0; j < 4; ++j) {
            float tin = __shfl(mj[j], src);
            if (seg > 0 && kap == sk) mj[j] = tin;
        }
        if (kap == sk) {
            #pragma unroll
            for (int j = 0; j < 4; ++j) {
                f32x4 c = __builtin_bit_cast(f32x4, acc[si][j]);
                const int ng = n0 + wn + j * 16 + (lane & 15);
                #pragma unroll
                for (int r = 0; r < 4; ++r) {
                    float rst = (mj[j] > 1.0f) ? 1.0f : 0.0f;
                    mj[j] = __fsub_rn(__fadd_rn(__fmul_rn(0.9f, mj[j]), c[r]), rst);
                    Dout[((size_t)(seg * 4 + r) * BSZ + b_idx) * N + ng] = (mj[j] > 1.0f) ? 1.0f : 0.0f;
                }
            }
        }
    }
}

// ================= bf16 GEMM (3-part split) — kept for the small GEMM0 =================
__global__ __launch_bounds__(256)
void snn_gemm_mfma_n(const __hip_bfloat16* __restrict__ A,
                     const __hip_bfloat16* __restrict__ Whi,
                     const __hip_bfloat16* __restrict__ Wmid,
                     const __hip_bfloat16* __restrict__ Wlo,
                     const float* __restrict__ bias,
                     float* __restrict__ C,
                     int M, int N, int K) {
    __shared__ __align__(16) unsigned short As[128 * 32];
    __shared__ __align__(16) unsigned short Bs[128 * 32];
    const int t    = threadIdx.x;
    const int wave = t >> 6;
    const int lane = t & 63;

    int m_idx = blockIdx.y, n_idx = blockIdx.x;
    const int m0 = m_idx * 128;
    const int n0 = n_idx * 128;
    const int wm = (wave & 1) * 64;
    const int wn = (wave >> 1) * 64;

    const int srow = lane >> 2;
    const int schk = ((lane & 3) + (lane >> 2) + (lane >> 4)) & 3;
    const int rho  = lane & 15;
    const int kap  = lane >> 4;
    const int foff = ((rho << 2) + ((kap - rho - (rho >> 2)) & 3)) * 8;   // shorts

    f32x4 acc[4][4] = {};

    const __hip_bfloat16* parts[3] = {Whi, Wmid, Wlo};
    for (int part = 0; part < 3; ++part) {
        const __hip_bfloat16* Bw = parts[part];
        for (int k0 = 0; k0 < K; k0 += 32) {
            __syncthreads();
            #pragma unroll
            for (int q = 0; q < 2; ++q) {
                int grp = wave * 2 + q;
                async16(A  + (size_t)(m0 + grp * 16 + srow) * K + k0 + schk * 8,
                        &As[grp * 512 + lane * 8]);
                async16(Bw + (size_t)(n0 + grp * 16 + srow) * K + k0 + schk * 8,
                        &Bs[grp * 512 + lane * 8]);
            }
            __syncthreads();

            bf16x8 af[4], bfr[4];
            #pragma unroll
            for (int i = 0; i < 4; ++i) {
                af[i]  = *(const bf16x8*)&As[((wm >> 4) + i) * 512 + foff];
                bfr[i] = *(const bf16x8*)&Bs[((wn >> 4) + i) * 512 + foff];
            }
            #pragma unroll
            for (int i = 0; i < 4; ++i)
                #pragma unroll
                for (int j = 0; j < 4; ++j)
                    acc[i][j] = __builtin_amdgcn_mfma_f32_16x16x32_bf16(af[i], bfr[j], acc[i][j], 0, 0, 0);
        }
    }

    #pragma unroll
    for (int i = 0; i < 4; ++i) {
        int mg = m0 + wm + i * 16 + (lane >> 4) * 4;
        #pragma unroll
        for (int j = 0; j < 4; ++j) {
            int ng = n0 + wn + j * 16 + (lane & 15);
            float bb = bias[ng];
            #pragma unroll
            for (int r = 0; r < 4; ++r)
                C[(size_t)(mg + r) * N + ng] = acc[i][j][r] + bb;
        }
    }
}

// ---------------- LIF layer 0 (broadcast), b-major i8 spike output ----------------
__global__ void snn_lif0_i8_bmaj(const float4* __restrict__ cur, uchar4* __restrict__ spk,
                                 int BH4, int H4) {
    int idx = blockIdx.x * blockDim.x + threadIdx.x;
    if (idx >= BH4) return;
    const int b  = idx / H4;
    const int h4 = idx - b * H4;
    uchar4* out = spk + (size_t)b * S_STEPS * H4 + h4;
    float m0 = 0.0f, m1 = 0.0f, m2 = 0.0f, m3 = 0.0f;
    float4 c = cur[idx];
    for (int s = 0; s < S_STEPS; ++s) {
        float r0 = (m0 > 1.0f) ? 1.0f : 0.0f;
        float r1 = (m1 > 1.0f) ? 1.0f : 0.0f;
        float r2 = (m2 > 1.0f) ? 1.0f : 0.0f;
        float r3 = (m3 > 1.0f) ? 1.0f : 0.0f;
        m0 = __fsub_rn(__fadd_rn(__fmul_rn(0.9f, m0), c.x), r0);
        m1 = __fsub_rn(__fadd_rn(__fmul_rn(0.9f, m1), c.y), r1);
        m2 = __fsub_rn(__fadd_rn(__fmul_rn(0.9f, m2), c.z), r2);
        m3 = __fsub_rn(__fadd_rn(__fmul_rn(0.9f, m3), c.w), r3);
        uchar4 o;
        o.x = (m0 > 1.0f) ? 1 : 0;
        o.y = (m1 > 1.0f) ? 1 : 0;
        o.z = (m2 > 1.0f) ? 1 : 0;
        o.w = (m3 > 1.0f) ? 1 : 0;
        out[(size_t)s * H4] = o;
    }
}

extern "C" void kernel_launch(void* const* d_in, const int* in_sizes, int n_in,
                              void* d_out, int out_size, void* d_ws, size_t ws_size,
                              hipStream_t stream) {
    const float* x  = (const float*)d_in[0];
    const float* W0 = (const float*)d_in[1];
    const float* b0 = (const float*)d_in[2];
    const float* W1 = (const float*)d_in[3];
    const float* b1 = (const float*)d_in[4];
    const float* W2 = (const float*)d_in[5];
    const float* b2 = (const float*)d_in[6];

    const int B = 256, T = 128, F = 512, H1 = 1024, H2 = 1024, H3 = 512;
    const int SB = S_STEPS * B;            // 16384

    // ---- workspace carve-up, all 16B aligned ----
    char* w = (char*)d_ws;
    signed char*    spk0 = (signed char*)w;                 w += (size_t)SB * H1;       // 16.7 MB
    signed char*    spk1 = (signed char*)w;                 w += (size_t)SB * H2;       // 16.7 MB
    __hip_bfloat16* r_bf = (__hip_bfloat16*)w;              w += (size_t)B * F * 2;     // 256 KB
    float*          cur0 = (float*)w;                       w += (size_t)B * H1 * 4;    // 1 MB
    __hip_bfloat16* W0s  = (__hip_bfloat16*)w;              w += (size_t)3 * H1 * F * 2;
    signed char*    W1q  = (signed char*)w;                 w += (size_t)3 * H2 * H1;   // 3 MB
    signed char*    W2q  = (signed char*)w;                 w += (size_t)3 * H3 * H2;   // 1.5 MB

    const int nW0 = H1 * F;

    // 1. merged prep: encoder (512 blocks) + W0 split (512) + W1/W2 quant (1536)
    snn_prep<<<dim3(2560), dim3(256), 0, stream>>>(
        (const float4*)x, (ushort4*)r_bf,
        (const float4*)W0, (ushort4*)W0s,
        (const float4*)W1, (const float4*)W2,
        (char4*)W1q, (char4*)W2q);

    // 2. cur0 = r @ W0^T + b0   [256 x 1024, K=512]  (bf16x3 path)
    snn_gemm_mfma_n<<<dim3(H1 / 128, B / 128), dim3(256), 0, stream>>>(
        r_bf, W0s, W0s + nW0, W0s + 2 * nW0, b0, cur0, B, H1, F);

    // 3. LIF layer 0 (broadcast) -> spk0 i8, b-major rows b*64+s
    snn_lif0_i8_bmaj<<<dim3(B * H1 / 4 / 256), dim3(256), 0, stream>>>(
        (const float4*)cur0, (uchar4*)spk0, B * H1 / 4, H1 / 4);

    // 4+5. cur1 = spk0 @ W1^T + b1, fused LIF -> spk1 i8 b-major [16384 x 1024, K=1024]
    snn_gemm_i8_w_lif<<<dim3(H2 / 256, SB / 128), dim3(256), 0, stream>>>(
        spk0, W1q, b1, spk1);

    // 6+7. cur2 = spk1 @ W2^T + b2, fused LIF -> d_out f32 [S, B, H3]
    snn_gemm_i8_n_lif<<<dim3(H3 / 128, SB / 128), dim3(256), 0, stream>>>(
        spk1, W2q, b2, (float*)d_out);
}

// Round 9
// 254.240 us; speedup vs baseline: 1.0424x; 1.0424x over previous
//
#include <hip/hip_runtime.h>
#include <hip/hip_bf16.h>

#define S_STEPS 64

typedef __bf16 bf16x8 __attribute__((ext_vector_type(8)));
typedef float  f32x4  __attribute__((ext_vector_type(4)));
typedef int    i32x4  __attribute__((ext_vector_type(4)));

// ---- async 16B global->LDS (wave-uniform base + lane*16 contiguous dest) ----
__device__ __forceinline__ void async16(const void* g, void* l) {
    __builtin_amdgcn_global_load_lds((const __attribute__((address_space(1))) void*)g,
                                     (__attribute__((address_space(3))) void*)l,
                                     16, 0, 0);
}

// =============== merged prep: encoder + W0 bf16x3 split + W1/W2 i8 quant ===============
// grid: [0,512) encoder | [512,1024) W0 split | [1024,2560) W1/W2 quant
__global__ void snn_prep(const float4* __restrict__ xv, ushort4* __restrict__ r,
                         const float4* __restrict__ W0, ushort4* __restrict__ w0out,
                         const float4* __restrict__ W1, const float4* __restrict__ W2,
                         char4* __restrict__ w1out, char4* __restrict__ w2out) {
    constexpr int T = 128, F4 = 128;          // F/4
    constexpr int NB_ENC = 512;               // (F4/64)*B
    constexpr int N0_4 = 1024 * 512 / 4;      // 131072
    constexpr int NB_W0 = N0_4 / 256;         // 512
    constexpr int N1_4 = 1024 * 1024 / 4;     // 262144
    constexpr int N2_4 = 512 * 1024 / 4;      // 131072
    __shared__ int4 red[4][64];

    const int bid = blockIdx.x;
    if (bid < NB_ENC) {
        // ---------------- delta encoder (T-parallel) ----------------
        const int f4i = threadIdx.x & 63;
        const int tc  = threadIdx.x >> 6;     // 0..3
        const int b   = bid >> 1;
        const int f4  = (bid & 1) * 64 + f4i;
        int c0 = 0, c1 = 0, c2 = 0, c3 = 0;
        if (b > 0) {
            const float4* xb = xv + ((size_t)b * T + tc * 32) * F4 + f4;
            const float4* xp = xb - (size_t)T * F4;
            for (int t = 0; t < 32; ++t) {
                float4 a = xb[(size_t)t * F4];
                float4 p = xp[(size_t)t * F4];
                c0 += (__fsub_rn(a.x, p.x) >= 0.2f) ? 1 : 0;
                c1 += (__fsub_rn(a.y, p.y) >= 0.2f) ? 1 : 0;
                c2 += (__fsub_rn(a.z, p.z) >= 0.2f) ? 1 : 0;
                c3 += (__fsub_rn(a.w, p.w) >= 0.2f) ? 1 : 0;
            }
        }
        red[tc][f4i] = int4{c0, c1, c2, c3};
        __syncthreads();
        if (tc == 0) {
            int4 a = red[0][f4i], bb = red[1][f4i], cc = red[2][f4i], dd = red[3][f4i];
            int s0 = a.x + bb.x + cc.x + dd.x;
            int s1 = a.y + bb.y + cc.y + dd.y;
            int s2 = a.z + bb.z + cc.z + dd.z;
            int s3 = a.w + bb.w + cc.w + dd.w;
            ushort4 o;
            o.x = __hip_bfloat16_raw(__float2bfloat16((float)s0 * (1.0f / 128.0f))).x;
            o.y = __hip_bfloat16_raw(__float2bfloat16((float)s1 * (1.0f / 128.0f))).x;
            o.z = __hip_bfloat16_raw(__float2bfloat16((float)s2 * (1.0f / 128.0f))).x;
            o.w = __hip_bfloat16_raw(__float2bfloat16((float)s3 * (1.0f / 128.0f))).x;
            r[(size_t)b * F4 + f4] = o;
        }
    } else if (bid < NB_ENC + NB_W0) {
        // ---------------- W0 -> bf16 hi/mid/lo (exact 3-way split) ----------------
        int j = (bid - NB_ENC) * 256 + threadIdx.x;
        float4 w = W0[j];
        float wv[4] = {w.x, w.y, w.z, w.w};
        unsigned short hv[4], mv[4], lv[4];
        #pragma unroll
        for (int q = 0; q < 4; ++q) {
            __hip_bfloat16 hh = __float2bfloat16(wv[q]);
            float r1 = __fsub_rn(wv[q], __bfloat162float(hh));   // exact
            __hip_bfloat16 mm = __float2bfloat16(r1);
            float r2 = __fsub_rn(r1, __bfloat162float(mm));      // exact
            hv[q] = __hip_bfloat16_raw(hh).x;
            mv[q] = __hip_bfloat16_raw(mm).x;
            lv[q] = __hip_bfloat16_raw(__float2bfloat16(r2)).x;
        }
        w0out[j]             = ushort4{hv[0], hv[1], hv[2], hv[3]};
        w0out[j + N0_4]      = ushort4{mv[0], mv[1], mv[2], mv[3]};
        w0out[j + 2 * N0_4]  = ushort4{lv[0], lv[1], lv[2], lv[3]};
    } else {
        // ---------------- W1/W2 -> i8 fixed-point digits [d2][d1][d0] ----------------
        // e = rint(w*2^27), |e| <= 2^22; e = d0 + 256*d1 + 65536*d2 (exact).
        int i = (bid - NB_ENC - NB_W0) * 256 + threadIdx.x;
        const float4* W; char4* out; int n4; int j = i;
        if (j < N1_4) { W = W1; out = w1out; n4 = N1_4; }
        else { j -= N1_4; W = W2; out = w2out; n4 = N2_4; }
        float4 w = W[j];
        float wv[4] = {w.x, w.y, w.z, w.w};
        signed char d2v[4], d1v[4], d0v[4];
        #pragma unroll
        for (int q = 0; q < 4; ++q) {
            int e  = __float2int_rn(wv[q] * 134217728.0f);       // w * 2^27
            int d0 = (int)(signed char)(e & 0xff);
            int e1 = (e - d0) >> 8;                              // exact
            int d1 = (int)(signed char)(e1 & 0xff);
            int d2 = (e1 - d1) >> 8;                             // exact, in [-64,64]
            d0v[q] = (signed char)d0;
            d1v[q] = (signed char)d1;
            d2v[q] = (signed char)d2;
        }
        out[j]          = make_char4(d2v[0], d2v[1], d2v[2], d2v[3]);
        out[j + n4]     = make_char4(d1v[0], d1v[1], d1v[2], d1v[3]);
        out[j + 2 * n4] = make_char4(d0v[0], d0v[1], d0v[2], d0v[3]);
    }
}

// Swizzled staging map (per 16-row x 64-byte group = 64 slots x 16B):
//   slot s holds global (row = s>>2, chunk16B = ((s&3)+(s>>2)+(s>>4)) & 3)
//   frag read slot(rho,kap) = 4*rho + ((kap - rho - (rho>>2)) & 3)
//
// B-MAJOR M-LAYOUT: GEMM M-row index = b*64 + s; wave's 64-row tile = one batch
// element, LIF scan fused in the epilogue (s = 4*seg + r, seg = i*4 + kap).
//
// TRIPLE-BUFFERED, ONE BARRIER PER TILE (R7-verified): body(i) stages buf (i+2)%3;
// that buffer's last reads (tile i-1, body(i-2)) completed before body(i-2)'s
// lgkmcnt(0), which precedes body(i-1)'s barrier -> single barrier per tile is
// safe.  vmcnt(6/4) keeps next tile's loads in flight.  M,N,K stay RUNTIME so
// the tile loop cannot be fully unrolled (R8: full unroll -> VGPR spill, +74MB
// scratch HBM traffic, -11 µs regression).

// ================= i8 GEMM A + fused LIF: block 128x256, wave 64x128 =================
__global__ __launch_bounds__(256, 2)
void snn_gemm_i8_w_lif(const signed char* __restrict__ A,
                       const signed char* __restrict__ Wq,
                       const float* __restrict__ bias,
                       signed char* __restrict__ Sout,   // spikes i8, rows b*64+s
                       int M, int N, int K) {
    __shared__ __align__(16) char As[3 * 8192];    // 3 x 8 groups x 1024B
    __shared__ __align__(16) char Bs[3 * 16384];   // 3 x 16 groups x 1024B
    const int t    = threadIdx.x;
    const int wave = t >> 6;
    const int lane = t & 63;

    int m_idx, n_idx;
    {
        int gx = gridDim.x, gy = gridDim.y;
        int flat = blockIdx.y * gx + blockIdx.x;
        if ((gy & 7) == 0) {
            int x = flat & 7, local = flat >> 3, h = gy >> 3;
            m_idx = x * h + (local % h);
            n_idx = local / h;
        } else { m_idx = blockIdx.y; n_idx = blockIdx.x; }
    }
    const int m0 = m_idx * 128;
    const int n0 = n_idx * 256;
    const int wm = (wave >> 1) * 64;
    const int wn = (wave & 1) * 128;

    const int srow = lane >> 2;
    const int schk = ((lane & 3) + (lane >> 2) + (lane >> 4)) & 3;
    const int rho  = lane & 15;
    const int kap  = lane >> 4;
    const int foff = ((rho << 2) + ((kap - rho - (rho >> 2)) & 3)) * 16;   // bytes

    const int KT = K >> 6;
    const int NT = 3 * KT;
    const size_t PK = (size_t)N * K;

    size_t aOff[2], bOff[4];
    #pragma unroll
    for (int q = 0; q < 2; ++q)
        aOff[q] = (size_t)(m0 + (wave * 2 + q) * 16 + srow) * K + schk * 16;
    #pragma unroll
    for (int q = 0; q < 4; ++q)
        bOff[q] = (size_t)(n0 + (wave * 4 + q) * 16 + srow) * K + schk * 16;

    i32x4 acc[4][8] = {};
    i32x4 afA[4], afB[4], bLo[4], bHi[4];

    auto stageT = [&](int p, int kt, int bsel) {
        const int kk = kt << 6;
        char* as = As + bsel * 8192;
        char* bs = Bs + bsel * 16384;
        #pragma unroll
        for (int q = 0; q < 2; ++q)
            async16(A + aOff[q] + kk, as + (wave * 2 + q) * 1024 + lane * 16);
        const signed char* Bw = Wq + (size_t)p * PK;
        #pragma unroll
        for (int q = 0; q < 4; ++q)
            async16(Bw + bOff[q] + kk, bs + (wave * 4 + q) * 1024 + lane * 16);
    };

    int sp = 0, skt = 2;          // next tile to stage
    int sbuf = 2, rbuf = 1;       // stage buffer (i+2)%3, read buffer (i+1)%3

    auto body = [&](int i, i32x4* afc, i32x4* afn) {
        if (i + 2 < NT) {
            stageT(sp, skt, sbuf);
            if (++skt == KT) { skt = 0; ++sp; }
            asm volatile("s_waitcnt vmcnt(6)" ::: "memory");   // tile i+1 landed
        } else {
            asm volatile("s_waitcnt vmcnt(0)" ::: "memory");
        }
        __builtin_amdgcn_s_barrier();                          // tile i+1 visible
        const char* as = As + rbuf * 8192;
        const char* bs = Bs + rbuf * 16384;
        #pragma unroll
        for (int q = 0; q < 4; ++q)
            afn[q] = *(const i32x4*)&as[((wm >> 4) + q) * 1024 + foff];
        #pragma unroll
        for (int q = 0; q < 4; ++q)
            bLo[q] = *(const i32x4*)&bs[((wn >> 4) + q) * 1024 + foff];
        __builtin_amdgcn_sched_barrier(0);                     // reads issued first
        #pragma unroll
        for (int q = 0; q < 4; ++q)
            #pragma unroll
            for (int j = 0; j < 4; ++j)
                acc[q][4 + j] = __builtin_amdgcn_mfma_i32_16x16x64_i8(afc[q], bHi[j], acc[q][4 + j], 0, 0, 0);
        #pragma unroll
        for (int q = 0; q < 4; ++q)
            bHi[q] = *(const i32x4*)&bs[((wn >> 4) + 4 + q) * 1024 + foff];
        asm volatile("s_waitcnt lgkmcnt(0)" ::: "memory");     // frags of i+1 in regs
        __builtin_amdgcn_sched_barrier(0);
        if (((i + 1) & (KT - 1)) == 0) {                       // Horner fold at part edge
            #pragma unroll
            for (int q = 0; q < 4; ++q)
                #pragma unroll
                for (int j = 0; j < 8; ++j)
                    acc[q][j] = acc[q][j] * 256;
        }
        #pragma unroll
        for (int q = 0; q < 4; ++q)
            #pragma unroll
            for (int j = 0; j < 4; ++j)
                acc[q][j] = __builtin_amdgcn_mfma_i32_16x16x64_i8(afn[q], bLo[j], acc[q][j], 0, 0, 0);
        sbuf = (sbuf == 2) ? 0 : sbuf + 1;
        rbuf = (rbuf == 2) ? 0 : rbuf + 1;
    };

    // prologue: stage tiles 0,1; read tile 0; lo-half of tile 0
    stageT(0, 0, 0);
    stageT(0, 1, 1);
    asm volatile("s_waitcnt vmcnt(6)" ::: "memory");
    __builtin_amdgcn_s_barrier();
    {
        const char* as = As;
        const char* bs = Bs;
        #pragma unroll
        for (int q = 0; q < 4; ++q)
            afA[q] = *(const i32x4*)&as[((wm >> 4) + q) * 1024 + foff];
        #pragma unroll
        for (int q = 0; q < 4; ++q) {
            bLo[q] = *(const i32x4*)&bs[((wn >> 4) + q) * 1024 + foff];
            bHi[q] = *(const i32x4*)&bs[((wn >> 4) + 4 + q) * 1024 + foff];
        }
    }
    asm volatile("s_waitcnt lgkmcnt(0)" ::: "memory");
    __builtin_amdgcn_sched_barrier(0);
    #pragma unroll
    for (int q = 0; q < 4; ++q)
        #pragma unroll
        for (int j = 0; j < 4; ++j)
            acc[q][j] = __builtin_amdgcn_mfma_i32_16x16x64_i8(afA[q], bLo[j], acc[q][j], 0, 0, 0);

    for (int i = 0; i < NT - 2; i += 2) {
        body(i, afA, afB);
        body(i + 1, afB, afA);
    }
    body(NT - 2, afA, afB);
    #pragma unroll
    for (int q = 0; q < 4; ++q)
        #pragma unroll
        for (int j = 0; j < 4; ++j)
            acc[q][4 + j] = __builtin_amdgcn_mfma_i32_16x16x64_i8(afB[q], bHi[j], acc[q][4 + j], 0, 0, 0);

    // ---------- fused LIF epilogue ----------
    const float SCALE = 7.450580596923828e-9f;   // 2^-27
    float bb[8];
    #pragma unroll
    for (int j = 0; j < 8; ++j)
        bb[j] = bias[n0 + wn + j * 16 + (lane & 15)];
    #pragma unroll
    for (int i = 0; i < 4; ++i)
        #pragma unroll
        for (int j = 0; j < 8; ++j) {
            i32x4 v = acc[i][j];
            f32x4 c;
            #pragma unroll
            for (int r = 0; r < 4; ++r)
                c[r] = (float)v[r] * SCALE + bb[j];
            acc[i][j] = __builtin_bit_cast(i32x4, c);
        }
    float mj[8] = {0.f, 0.f, 0.f, 0.f, 0.f, 0.f, 0.f, 0.f};
    signed char* So = Sout + (size_t)(m0 + wm) * N;   // rows b*64 + s
    #pragma unroll
    for (int seg = 0; seg < 16; ++seg) {
        const int si = seg >> 2, sk = seg & 3;
        const int src = (lane & 15) | (((sk + 3) & 3) << 4);
        #pragma unroll
        for (int j = 0; j < 8; ++j) {
            float tin = __shfl(mj[j], src);
            if (seg > 0 && kap == sk) mj[j] = tin;
        }
        if (kap == sk) {
            #pragma unroll
            for (int j = 0; j < 8; ++j) {
                f32x4 c = __builtin_bit_cast(f32x4, acc[si][j]);
                const int ng = n0 + wn + j * 16 + (lane & 15);
                #pragma unroll
                for (int r = 0; r < 4; ++r) {
                    float rst = (mj[j] > 1.0f) ? 1.0f : 0.0f;
                    mj[j] = __fsub_rn(__fadd_rn(__fmul_rn(0.9f, mj[j]), c[r]), rst);
                    So[(size_t)(seg * 4 + r) * N + ng] = (mj[j] > 1.0f) ? (signed char)1 : (signed char)0;
                }
            }
        }
    }
}

// ================= i8 GEMM B + fused LIF -> f32 output: block 128x128, wave 64x64 =====
__global__ __launch_bounds__(256, 2)
void snn_gemm_i8_n_lif(const signed char* __restrict__ A,
                       const signed char* __restrict__ Wq,
                       const float* __restrict__ bias,
                       float* __restrict__ Dout,        // [S, Bsz, N] f32 spikes
                       int M, int N, int K, int Bsz) {
    __shared__ __align__(16) char As[3 * 8192];
    __shared__ __align__(16) char Bs[3 * 8192];
    const int t    = threadIdx.x;
    const int wave = t >> 6;
    const int lane = t & 63;

    int m_idx, n_idx;
    {
        int gx = gridDim.x, gy = gridDim.y;
        int flat = blockIdx.y * gx + blockIdx.x;
        if ((gy & 7) == 0) {
            int x = flat & 7, local = flat >> 3, h = gy >> 3;
            m_idx = x * h + (local % h);
            n_idx = local / h;
        } else { m_idx = blockIdx.y; n_idx = blockIdx.x; }
    }
    const int m0 = m_idx * 128;
    const int n0 = n_idx * 128;
    const int wm = (wave & 1) * 64;
    const int wn = (wave >> 1) * 64;

    const int srow = lane >> 2;
    const int schk = ((lane & 3) + (lane >> 2) + (lane >> 4)) & 3;
    const int rho  = lane & 15;
    const int kap  = lane >> 4;
    const int foff = ((rho << 2) + ((kap - rho - (rho >> 2)) & 3)) * 16;   // bytes

    const int KT = K >> 6;
    const int NT = 3 * KT;
    const size_t PK = (size_t)N * K;

    size_t aOff[2], bOff[2];
    #pragma unroll
    for (int q = 0; q < 2; ++q) {
        aOff[q] = (size_t)(m0 + (wave * 2 + q) * 16 + srow) * K + schk * 16;
        bOff[q] = (size_t)(n0 + (wave * 2 + q) * 16 + srow) * K + schk * 16;
    }

    i32x4 acc[4][4] = {};
    i32x4 afA[4], afB[4], bLo[2], bHi[2];

    auto stageT = [&](int p, int kt, int bsel) {
        const int kk = kt << 6;
        char* as = As + bsel * 8192;
        char* bs = Bs + bsel * 8192;
        const signed char* Bw = Wq + (size_t)p * PK;
        #pragma unroll
        for (int q = 0; q < 2; ++q) {
            async16(A  + aOff[q] + kk, as + (wave * 2 + q) * 1024 + lane * 16);
            async16(Bw + bOff[q] + kk, bs + (wave * 2 + q) * 1024 + lane * 16);
        }
    };

    int sp = 0, skt = 2;
    int sbuf = 2, rbuf = 1;

    auto body = [&](int i, i32x4* afc, i32x4* afn) {
        if (i + 2 < NT) {
            stageT(sp, skt, sbuf);
            if (++skt == KT) { skt = 0; ++sp; }
            asm volatile("s_waitcnt vmcnt(4)" ::: "memory");
        } else {
            asm volatile("s_waitcnt vmcnt(0)" ::: "memory");
        }
        __builtin_amdgcn_s_barrier();
        const char* as = As + rbuf * 8192;
        const char* bs = Bs + rbuf * 8192;
        #pragma unroll
        for (int q = 0; q < 4; ++q)
            afn[q] = *(const i32x4*)&as[((wm >> 4) + q) * 1024 + foff];
        #pragma unroll
        for (int q = 0; q < 2; ++q)
            bLo[q] = *(const i32x4*)&bs[((wn >> 4) + q) * 1024 + foff];
        __builtin_amdgcn_sched_barrier(0);
        #pragma unroll
        for (int q = 0; q < 4; ++q)
            #pragma unroll
            for (int j = 0; j < 2; ++j)
                acc[q][2 + j] = __builtin_amdgcn_mfma_i32_16x16x64_i8(afc[q], bHi[j], acc[q][2 + j], 0, 0, 0);
        #pragma unroll
        for (int q = 0; q < 2; ++q)
            bHi[q] = *(const i32x4*)&bs[((wn >> 4) + 2 + q) * 1024 + foff];
        asm volatile("s_waitcnt lgkmcnt(0)" ::: "memory");
        __builtin_amdgcn_sched_barrier(0);
        if (((i + 1) & (KT - 1)) == 0) {
            #pragma unroll
            for (int q = 0; q < 4; ++q)
                #pragma unroll
                for (int j = 0; j < 4; ++j)
                    acc[q][j] = acc[q][j] * 256;
        }
        #pragma unroll
        for (int q = 0; q < 4; ++q)
            #pragma unroll
            for (int j = 0; j < 2; ++j)
                acc[q][j] = __builtin_amdgcn_mfma_i32_16x16x64_i8(afn[q], bLo[j], acc[q][j], 0, 0, 0);
        sbuf = (sbuf == 2) ? 0 : sbuf + 1;
        rbuf = (rbuf == 2) ? 0 : rbuf + 1;
    };

    stageT(0, 0, 0);
    stageT(0, 1, 1);
    asm volatile("s_waitcnt vmcnt(4)" ::: "memory");
    __builtin_amdgcn_s_barrier();
    {
        const char* as = As;
        const char* bs = Bs;
        #pragma unroll
        for (int q = 0; q < 4; ++q)
            afA[q] = *(const i32x4*)&as[((wm >> 4) + q) * 1024 + foff];
        #pragma unroll
        for (int q = 0; q < 2; ++q) {
            bLo[q] = *(const i32x4*)&bs[((wn >> 4) + q) * 1024 + foff];
            bHi[q] = *(const i32x4*)&bs[((wn >> 4) + 2 + q) * 1024 + foff];
        }
    }
    asm volatile("s_waitcnt lgkmcnt(0)" ::: "memory");
    __builtin_amdgcn_sched_barrier(0);
    #pragma unroll
    for (int q = 0; q < 4; ++q)
        #pragma unroll
        for (int j = 0; j < 2; ++j)
            acc[q][j] = __builtin_amdgcn_mfma_i32_16x16x64_i8(afA[q], bLo[j], acc[q][j], 0, 0, 0);

    for (int i = 0; i < NT - 2; i += 2) {
        body(i, afA, afB);
        body(i + 1, afB, afA);
    }
    body(NT - 2, afA, afB);
    #pragma unroll
    for (int q = 0; q < 4; ++q)
        #pragma unroll
        for (int j = 0; j < 2; ++j)
            acc[q][2 + j] = __builtin_amdgcn_mfma_i32_16x16x64_i8(afB[q], bHi[j], acc[q][2 + j], 0, 0, 0);

    // ---------- fused LIF epilogue -> f32 spikes [S, Bsz, N] ----------
    const float SCALE = 7.450580596923828e-9f;   // 2^-27
    float bb[4];
    #pragma unroll
    for (int j = 0; j < 4; ++j)
        bb[j] = bias[n0 + wn + j * 16 + (lane & 15)];
    #pragma unroll
    for (int i = 0; i < 4; ++i)
        #pragma unroll
        for (int j = 0; j < 4; ++j) {
            i32x4 v = acc[i][j];
            f32x4 c;
            #pragma unroll
            for (int r = 0; r < 4; ++r)
                c[r] = (float)v[r] * SCALE + bb[j];
            acc[i][j] = __builtin_bit_cast(i32x4, c);
        }
    float mj[4] = {0.f, 0.f, 0.f, 0.f};
    const int b_idx = (m0 + wm) >> 6;
    #pragma unroll
    for (int seg = 0; seg < 16; ++seg) {
        const int si = seg >> 2, sk = seg & 3;
        const int src = (lane & 15) | (((sk + 3) & 3) << 4);
        #pragma unroll
        for (int j = 0; j < 4; ++j) {
            float tin = __shfl(mj[j], src);
            if (seg > 0 && kap == sk) mj[j] = tin;
        }
        if (kap == sk) {
            #pragma unroll
            for (int j = 0; j < 4; ++j) {
                f32x4 c = __builtin_bit_cast(f32x4, acc[si][j]);
                const int ng = n0 + wn + j * 16 + (lane & 15);
                #pragma unroll
                for (int r = 0; r < 4; ++r) {
                    float rst = (mj[j] > 1.0f) ? 1.0f : 0.0f;
                    mj[j] = __fsub_rn(__fadd_rn(__fmul_rn(0.9f, mj[j]), c[r]), rst);
                    Dout[((size_t)(seg * 4 + r) * Bsz + b_idx) * N + ng] = (mj[j] > 1.0f) ? 1.0f : 0.0f;
                }
            }
        }
    }
}

// ================= bf16 GEMM (3-part split) — kept for the small GEMM0 =================
__global__ __launch_bounds__(256)
void snn_gemm_mfma_n(const __hip_bfloat16* __restrict__ A,
                     const __hip_bfloat16* __restrict__ Whi,
                     const __hip_bfloat16* __restrict__ Wmid,
                     const __hip_bfloat16* __restrict__ Wlo,
                     const float* __restrict__ bias,
                     float* __restrict__ C,
                     int M, int N, int K) {
    __shared__ __align__(16) unsigned short As[128 * 32];
    __shared__ __align__(16) unsigned short Bs[128 * 32];
    const int t    = threadIdx.x;
    const int wave = t >> 6;
    const int lane = t & 63;

    int m_idx = blockIdx.y, n_idx = blockIdx.x;
    const int m0 = m_idx * 128;
    const int n0 = n_idx * 128;
    const int wm = (wave & 1) * 64;
    const int wn = (wave >> 1) * 64;

    const int srow = lane >> 2;
    const int schk = ((lane & 3) + (lane >> 2) + (lane >> 4)) & 3;
    const int rho  = lane & 15;
    const int kap  = lane >> 4;
    const int foff = ((rho << 2) + ((kap - rho - (rho >> 2)) & 3)) * 8;   // shorts

    f32x4 acc[4][4] = {};

    const __hip_bfloat16* parts[3] = {Whi, Wmid, Wlo};
    for (int part = 0; part < 3; ++part) {
        const __hip_bfloat16* Bw = parts[part];
        for (int k0 = 0; k0 < K; k0 += 32) {
            __syncthreads();
            #pragma unroll
            for (int q = 0; q < 2; ++q) {
                int grp = wave * 2 + q;
                async16(A  + (size_t)(m0 + grp * 16 + srow) * K + k0 + schk * 8,
                        &As[grp * 512 + lane * 8]);
                async16(Bw + (size_t)(n0 + grp * 16 + srow) * K + k0 + schk * 8,
                        &Bs[grp * 512 + lane * 8]);
            }
            __syncthreads();

            bf16x8 af[4], bfr[4];
            #pragma unroll
            for (int i = 0; i < 4; ++i) {
                af[i]  = *(const bf16x8*)&As[((wm >> 4) + i) * 512 + foff];
                bfr[i] = *(const bf16x8*)&Bs[((wn >> 4) + i) * 512 + foff];
            }
            #pragma unroll
            for (int i = 0; i < 4; ++i)
                #pragma unroll
                for (int j = 0; j < 4; ++j)
                    acc[i][j] = __builtin_amdgcn_mfma_f32_16x16x32_bf16(af[i], bfr[j], acc[i][j], 0, 0, 0);
        }
    }

    #pragma unroll
    for (int i = 0; i < 4; ++i) {
        int mg = m0 + wm + i * 16 + (lane >> 4) * 4;
        #pragma unroll
        for (int j = 0; j < 4; ++j) {
            int ng = n0 + wn + j * 16 + (lane & 15);
            float bb = bias[ng];
            #pragma unroll
            for (int r = 0; r < 4; ++r)
                C[(size_t)(mg + r) * N + ng] = acc[i][j][r] + bb;
        }
    }
}

// ---------------- LIF layer 0 (broadcast), b-major i8 spike output ----------------
__global__ void snn_lif0_i8_bmaj(const float4* __restrict__ cur, uchar4* __restrict__ spk,
                                 int BH4, int H4) {
    int idx = blockIdx.x * blockDim.x + threadIdx.x;
    if (idx >= BH4) return;
    const int b  = idx / H4;
    const int h4 = idx - b * H4;
    uchar4* out = spk + (size_t)b * S_STEPS * H4 + h4;
    float m0 = 0.0f, m1 = 0.0f, m2 = 0.0f, m3 = 0.0f;
    float4 c = cur[idx];
    for (int s = 0; s < S_STEPS; ++s) {
        float r0 = (m0 > 1.0f) ? 1.0f : 0.0f;
        float r1 = (m1 > 1.0f) ? 1.0f : 0.0f;
        float r2 = (m2 > 1.0f) ? 1.0f : 0.0f;
        float r3 = (m3 > 1.0f) ? 1.0f : 0.0f;
        m0 = __fsub_rn(__fadd_rn(__fmul_rn(0.9f, m0), c.x), r0);
        m1 = __fsub_rn(__fadd_rn(__fmul_rn(0.9f, m1), c.y), r1);
        m2 = __fsub_rn(__fadd_rn(__fmul_rn(0.9f, m2), c.z), r2);
        m3 = __fsub_rn(__fadd_rn(__fmul_rn(0.9f, m3), c.w), r3);
        uchar4 o;
        o.x = (m0 > 1.0f) ? 1 : 0;
        o.y = (m1 > 1.0f) ? 1 : 0;
        o.z = (m2 > 1.0f) ? 1 : 0;
        o.w = (m3 > 1.0f) ? 1 : 0;
        out[(size_t)s * H4] = o;
    }
}

extern "C" void kernel_launch(void* const* d_in, const int* in_sizes, int n_in,
                              void* d_out, int out_size, void* d_ws, size_t ws_size,
                              hipStream_t stream) {
    const float* x  = (const float*)d_in[0];
    const float* W0 = (const float*)d_in[1];
    const float* b0 = (const float*)d_in[2];
    const float* W1 = (const float*)d_in[3];
    const float* b1 = (const float*)d_in[4];
    const float* W2 = (const float*)d_in[5];
    const float* b2 = (const float*)d_in[6];

    const int B = 256, T = 128, F = 512, H1 = 1024, H2 = 1024, H3 = 512;
    const int SB = S_STEPS * B;            // 16384

    // ---- workspace carve-up, all 16B aligned ----
    char* w = (char*)d_ws;
    signed char*    spk0 = (signed char*)w;                 w += (size_t)SB * H1;       // 16.7 MB
    signed char*    spk1 = (signed char*)w;                 w += (size_t)SB * H2;       // 16.7 MB
    __hip_bfloat16* r_bf = (__hip_bfloat16*)w;              w += (size_t)B * F * 2;     // 256 KB
    float*          cur0 = (float*)w;                       w += (size_t)B * H1 * 4;    // 1 MB
    __hip_bfloat16* W0s  = (__hip_bfloat16*)w;              w += (size_t)3 * H1 * F * 2;
    signed char*    W1q  = (signed char*)w;                 w += (size_t)3 * H2 * H1;   // 3 MB
    signed char*    W2q  = (signed char*)w;                 w += (size_t)3 * H3 * H2;   // 1.5 MB

    const int nW0 = H1 * F;

    // 1. merged prep: encoder (512 blocks) + W0 split (512) + W1/W2 quant (1536)
    snn_prep<<<dim3(2560), dim3(256), 0, stream>>>(
        (const float4*)x, (ushort4*)r_bf,
        (const float4*)W0, (ushort4*)W0s,
        (const float4*)W1, (const float4*)W2,
        (char4*)W1q, (char4*)W2q);

    // 2. cur0 = r @ W0^T + b0   [256 x 1024, K=512]  (bf16x3 path)
    snn_gemm_mfma_n<<<dim3(H1 / 128, B / 128), dim3(256), 0, stream>>>(
        r_bf, W0s, W0s + nW0, W0s + 2 * nW0, b0, cur0, B, H1, F);

    // 3. LIF layer 0 (broadcast) -> spk0 i8, b-major rows b*64+s
    snn_lif0_i8_bmaj<<<dim3(B * H1 / 4 / 256), dim3(256), 0, stream>>>(
        (const float4*)cur0, (uchar4*)spk0, B * H1 / 4, H1 / 4);

    // 4+5. cur1 = spk0 @ W1^T + b1, fused LIF -> spk1 i8 b-major [16384 x 1024, K=1024]
    snn_gemm_i8_w_lif<<<dim3(H2 / 256, SB / 128), dim3(256), 0, stream>>>(
        spk0, W1q, b1, spk1, SB, H2, H1);

    // 6+7. cur2 = spk1 @ W2^T + b2, fused LIF -> d_out f32 [S, B, H3]
    snn_gemm_i8_n_lif<<<dim3(H3 / 128, SB / 128), dim3(256), 0, stream>>>(
        spk1, W2q, b2, (float*)d_out, SB, H3, H2, B);
}

// Round 10
// 233.067 us; speedup vs baseline: 1.1371x; 1.0908x over previous
//
#include <hip/hip_runtime.h>
#include <hip/hip_bf16.h>

#define S_STEPS 64

typedef __bf16 bf16x8 __attribute__((ext_vector_type(8)));
typedef float  f32x4  __attribute__((ext_vector_type(4)));
typedef int    i32x4  __attribute__((ext_vector_type(4)));

// ---- async 16B global->LDS (wave-uniform base + lane*16 contiguous dest) ----
__device__ __forceinline__ void async16(const void* g, void* l) {
    __builtin_amdgcn_global_load_lds((const __attribute__((address_space(1))) void*)g,
                                     (__attribute__((address_space(3))) void*)l,
                                     16, 0, 0);
}

// =============== merged prep: encoder + W0 bf16x3 split + W1/W2 i8 quant ===============
// grid: [0,512) encoder | [512,1024) W0 split | [1024,2560) W1/W2 quant
__global__ void snn_prep(const float4* __restrict__ xv, ushort4* __restrict__ r,
                         const float4* __restrict__ W0, ushort4* __restrict__ w0out,
                         const float4* __restrict__ W1, const float4* __restrict__ W2,
                         char4* __restrict__ w1out, char4* __restrict__ w2out) {
    constexpr int T = 128, F4 = 128;          // F/4
    constexpr int NB_ENC = 512;               // (F4/64)*B
    constexpr int N0_4 = 1024 * 512 / 4;      // 131072
    constexpr int NB_W0 = N0_4 / 256;         // 512
    constexpr int N1_4 = 1024 * 1024 / 4;     // 262144
    constexpr int N2_4 = 512 * 1024 / 4;      // 131072
    __shared__ int4 red[4][64];

    const int bid = blockIdx.x;
    if (bid < NB_ENC) {
        // ---------------- delta encoder (T-parallel) ----------------
        const int f4i = threadIdx.x & 63;
        const int tc  = threadIdx.x >> 6;     // 0..3
        const int b   = bid >> 1;
        const int f4  = (bid & 1) * 64 + f4i;
        int c0 = 0, c1 = 0, c2 = 0, c3 = 0;
        if (b > 0) {
            const float4* xb = xv + ((size_t)b * T + tc * 32) * F4 + f4;
            const float4* xp = xb - (size_t)T * F4;
            for (int t = 0; t < 32; ++t) {
                float4 a = xb[(size_t)t * F4];
                float4 p = xp[(size_t)t * F4];
                c0 += (__fsub_rn(a.x, p.x) >= 0.2f) ? 1 : 0;
                c1 += (__fsub_rn(a.y, p.y) >= 0.2f) ? 1 : 0;
                c2 += (__fsub_rn(a.z, p.z) >= 0.2f) ? 1 : 0;
                c3 += (__fsub_rn(a.w, p.w) >= 0.2f) ? 1 : 0;
            }
        }
        red[tc][f4i] = int4{c0, c1, c2, c3};
        __syncthreads();
        if (tc == 0) {
            int4 a = red[0][f4i], bb = red[1][f4i], cc = red[2][f4i], dd = red[3][f4i];
            int s0 = a.x + bb.x + cc.x + dd.x;
            int s1 = a.y + bb.y + cc.y + dd.y;
            int s2 = a.z + bb.z + cc.z + dd.z;
            int s3 = a.w + bb.w + cc.w + dd.w;
            ushort4 o;
            o.x = __hip_bfloat16_raw(__float2bfloat16((float)s0 * (1.0f / 128.0f))).x;
            o.y = __hip_bfloat16_raw(__float2bfloat16((float)s1 * (1.0f / 128.0f))).x;
            o.z = __hip_bfloat16_raw(__float2bfloat16((float)s2 * (1.0f / 128.0f))).x;
            o.w = __hip_bfloat16_raw(__float2bfloat16((float)s3 * (1.0f / 128.0f))).x;
            r[(size_t)b * F4 + f4] = o;
        }
    } else if (bid < NB_ENC + NB_W0) {
        // ---------------- W0 -> bf16 hi/mid/lo (exact 3-way split) ----------------
        int j = (bid - NB_ENC) * 256 + threadIdx.x;
        float4 w = W0[j];
        float wv[4] = {w.x, w.y, w.z, w.w};
        unsigned short hv[4], mv[4], lv[4];
        #pragma unroll
        for (int q = 0; q < 4; ++q) {
            __hip_bfloat16 hh = __float2bfloat16(wv[q]);
            float r1 = __fsub_rn(wv[q], __bfloat162float(hh));   // exact
            __hip_bfloat16 mm = __float2bfloat16(r1);
            float r2 = __fsub_rn(r1, __bfloat162float(mm));      // exact
            hv[q] = __hip_bfloat16_raw(hh).x;
            mv[q] = __hip_bfloat16_raw(mm).x;
            lv[q] = __hip_bfloat16_raw(__float2bfloat16(r2)).x;
        }
        w0out[j]             = ushort4{hv[0], hv[1], hv[2], hv[3]};
        w0out[j + N0_4]      = ushort4{mv[0], mv[1], mv[2], mv[3]};
        w0out[j + 2 * N0_4]  = ushort4{lv[0], lv[1], lv[2], lv[3]};
    } else {
        // ---------------- W1/W2 -> i8 fixed-point digits [d2][d1][d0] ----------------
        // e = rint(w*2^27), |e| <= 2^22; e = d0 + 256*d1 + 65536*d2 (exact).
        int i = (bid - NB_ENC - NB_W0) * 256 + threadIdx.x;
        const float4* W; char4* out; int n4; int j = i;
        if (j < N1_4) { W = W1; out = w1out; n4 = N1_4; }
        else { j -= N1_4; W = W2; out = w2out; n4 = N2_4; }
        float4 w = W[j];
        float wv[4] = {w.x, w.y, w.z, w.w};
        signed char d2v[4], d1v[4], d0v[4];
        #pragma unroll
        for (int q = 0; q < 4; ++q) {
            int e  = __float2int_rn(wv[q] * 134217728.0f);       // w * 2^27
            int d0 = (int)(signed char)(e & 0xff);
            int e1 = (e - d0) >> 8;                              // exact
            int d1 = (int)(signed char)(e1 & 0xff);
            int d2 = (e1 - d1) >> 8;                             // exact, in [-64,64]
            d0v[q] = (signed char)d0;
            d1v[q] = (signed char)d1;
            d2v[q] = (signed char)d2;
        }
        out[j]          = make_char4(d2v[0], d2v[1], d2v[2], d2v[3]);
        out[j + n4]     = make_char4(d1v[0], d1v[1], d1v[2], d1v[3]);
        out[j + 2 * n4] = make_char4(d0v[0], d0v[1], d0v[2], d0v[3]);
    }
}

// Swizzled staging map (per 16-row x 64-byte group = 64 slots x 16B):
//   slot s holds global (row = s>>2, chunk16B = ((s&3)+(s>>2)+(s>>4)) & 3)
//   frag read slot(rho,kap) = 4*rho + ((kap - rho - (rho>>2)) & 3)
//
// B-MAJOR M-LAYOUT: GEMM M-row index = b*64 + s; wave's 64-row tile = one batch
// element, LIF scan fused in the epilogue (s = 4*seg + r, seg = i*4 + kap).
//
// TRIPLE-BUFFERED, ONE BARRIER PER TILE (R7-verified): body(i) stages buf (i+2)%3;
// safe because that buffer's last reads finished before the previous barrier.
// vmcnt(6/4) keeps next tile's loads in flight.  M,N,K stay RUNTIME in the big
// GEMMs so the tile loop cannot fully unroll (R8: full unroll -> VGPR spill).

// ================= i8 GEMM A + fused LIF: block 128x256, wave 64x128 =================
__global__ __launch_bounds__(256, 2)
void snn_gemm_i8_w_lif(const signed char* __restrict__ A,
                       const signed char* __restrict__ Wq,
                       const float* __restrict__ bias,
                       signed char* __restrict__ Sout,   // spikes i8, rows b*64+s
                       int M, int N, int K) {
    __shared__ __align__(16) char As[3 * 8192];    // 3 x 8 groups x 1024B
    __shared__ __align__(16) char Bs[3 * 16384];   // 3 x 16 groups x 1024B
    const int t    = threadIdx.x;
    const int wave = t >> 6;
    const int lane = t & 63;

    int m_idx, n_idx;
    {
        int gx = gridDim.x, gy = gridDim.y;
        int flat = blockIdx.y * gx + blockIdx.x;
        if ((gy & 7) == 0) {
            int x = flat & 7, local = flat >> 3, h = gy >> 3;
            m_idx = x * h + (local % h);
            n_idx = local / h;
        } else { m_idx = blockIdx.y; n_idx = blockIdx.x; }
    }
    const int m0 = m_idx * 128;
    const int n0 = n_idx * 256;
    const int wm = (wave >> 1) * 64;
    const int wn = (wave & 1) * 128;

    const int srow = lane >> 2;
    const int schk = ((lane & 3) + (lane >> 2) + (lane >> 4)) & 3;
    const int rho  = lane & 15;
    const int kap  = lane >> 4;
    const int foff = ((rho << 2) + ((kap - rho - (rho >> 2)) & 3)) * 16;   // bytes

    const int KT = K >> 6;
    const int NT = 3 * KT;
    const size_t PK = (size_t)N * K;

    size_t aOff[2], bOff[4];
    #pragma unroll
    for (int q = 0; q < 2; ++q)
        aOff[q] = (size_t)(m0 + (wave * 2 + q) * 16 + srow) * K + schk * 16;
    #pragma unroll
    for (int q = 0; q < 4; ++q)
        bOff[q] = (size_t)(n0 + (wave * 4 + q) * 16 + srow) * K + schk * 16;

    i32x4 acc[4][8] = {};
    i32x4 afA[4], afB[4], bLo[4], bHi[4];

    auto stageT = [&](int p, int kt, int bsel) {
        const int kk = kt << 6;
        char* as = As + bsel * 8192;
        char* bs = Bs + bsel * 16384;
        #pragma unroll
        for (int q = 0; q < 2; ++q)
            async16(A + aOff[q] + kk, as + (wave * 2 + q) * 1024 + lane * 16);
        const signed char* Bw = Wq + (size_t)p * PK;
        #pragma unroll
        for (int q = 0; q < 4; ++q)
            async16(Bw + bOff[q] + kk, bs + (wave * 4 + q) * 1024 + lane * 16);
    };

    int sp = 0, skt = 2;          // next tile to stage
    int sbuf = 2, rbuf = 1;       // stage buffer (i+2)%3, read buffer (i+1)%3

    auto body = [&](int i, i32x4* afc, i32x4* afn) {
        if (i + 2 < NT) {
            stageT(sp, skt, sbuf);
            if (++skt == KT) { skt = 0; ++sp; }
            asm volatile("s_waitcnt vmcnt(6)" ::: "memory");   // tile i+1 landed
        } else {
            asm volatile("s_waitcnt vmcnt(0)" ::: "memory");
        }
        __builtin_amdgcn_s_barrier();                          // tile i+1 visible
        const char* as = As + rbuf * 8192;
        const char* bs = Bs + rbuf * 16384;
        #pragma unroll
        for (int q = 0; q < 4; ++q)
            afn[q] = *(const i32x4*)&as[((wm >> 4) + q) * 1024 + foff];
        #pragma unroll
        for (int q = 0; q < 4; ++q)
            bLo[q] = *(const i32x4*)&bs[((wn >> 4) + q) * 1024 + foff];
        __builtin_amdgcn_sched_barrier(0);                     // reads issued first
        #pragma unroll
        for (int q = 0; q < 4; ++q)
            #pragma unroll
            for (int j = 0; j < 4; ++j)
                acc[q][4 + j] = __builtin_amdgcn_mfma_i32_16x16x64_i8(afc[q], bHi[j], acc[q][4 + j], 0, 0, 0);
        #pragma unroll
        for (int q = 0; q < 4; ++q)
            bHi[q] = *(const i32x4*)&bs[((wn >> 4) + 4 + q) * 1024 + foff];
        asm volatile("s_waitcnt lgkmcnt(0)" ::: "memory");     // frags of i+1 in regs
        __builtin_amdgcn_sched_barrier(0);
        if (((i + 1) & (KT - 1)) == 0) {                       // Horner fold at part edge
            #pragma unroll
            for (int q = 0; q < 4; ++q)
                #pragma unroll
                for (int j = 0; j < 8; ++j)
                    acc[q][j] = acc[q][j] * 256;
        }
        #pragma unroll
        for (int q = 0; q < 4; ++q)
            #pragma unroll
            for (int j = 0; j < 4; ++j)
                acc[q][j] = __builtin_amdgcn_mfma_i32_16x16x64_i8(afn[q], bLo[j], acc[q][j], 0, 0, 0);
        sbuf = (sbuf == 2) ? 0 : sbuf + 1;
        rbuf = (rbuf == 2) ? 0 : rbuf + 1;
    };

    // prologue: stage tiles 0,1; read tile 0; lo-half of tile 0
    stageT(0, 0, 0);
    stageT(0, 1, 1);
    asm volatile("s_waitcnt vmcnt(6)" ::: "memory");
    __builtin_amdgcn_s_barrier();
    {
        const char* as = As;
        const char* bs = Bs;
        #pragma unroll
        for (int q = 0; q < 4; ++q)
            afA[q] = *(const i32x4*)&as[((wm >> 4) + q) * 1024 + foff];
        #pragma unroll
        for (int q = 0; q < 4; ++q) {
            bLo[q] = *(const i32x4*)&bs[((wn >> 4) + q) * 1024 + foff];
            bHi[q] = *(const i32x4*)&bs[((wn >> 4) + 4 + q) * 1024 + foff];
        }
    }
    asm volatile("s_waitcnt lgkmcnt(0)" ::: "memory");
    __builtin_amdgcn_sched_barrier(0);
    #pragma unroll
    for (int q = 0; q < 4; ++q)
        #pragma unroll
        for (int j = 0; j < 4; ++j)
            acc[q][j] = __builtin_amdgcn_mfma_i32_16x16x64_i8(afA[q], bLo[j], acc[q][j], 0, 0, 0);

    for (int i = 0; i < NT - 2; i += 2) {
        body(i, afA, afB);
        body(i + 1, afB, afA);
    }
    body(NT - 2, afA, afB);
    #pragma unroll
    for (int q = 0; q < 4; ++q)
        #pragma unroll
        for (int j = 0; j < 4; ++j)
            acc[q][4 + j] = __builtin_amdgcn_mfma_i32_16x16x64_i8(afB[q], bHi[j], acc[q][4 + j], 0, 0, 0);

    // ---------- fused LIF epilogue ----------
    const float SCALE = 7.450580596923828e-9f;   // 2^-27
    float bb[8];
    #pragma unroll
    for (int j = 0; j < 8; ++j)
        bb[j] = bias[n0 + wn + j * 16 + (lane & 15)];
    #pragma unroll
    for (int i = 0; i < 4; ++i)
        #pragma unroll
        for (int j = 0; j < 8; ++j) {
            i32x4 v = acc[i][j];
            f32x4 c;
            #pragma unroll
            for (int r = 0; r < 4; ++r)
                c[r] = (float)v[r] * SCALE + bb[j];
            acc[i][j] = __builtin_bit_cast(i32x4, c);
        }
    float mj[8] = {0.f, 0.f, 0.f, 0.f, 0.f, 0.f, 0.f, 0.f};
    signed char* So = Sout + (size_t)(m0 + wm) * N;   // rows b*64 + s
    #pragma unroll
    for (int seg = 0; seg < 16; ++seg) {
        const int si = seg >> 2, sk = seg & 3;
        const int src = (lane & 15) | (((sk + 3) & 3) << 4);
        #pragma unroll
        for (int j = 0; j < 8; ++j) {
            float tin = __shfl(mj[j], src);
            if (seg > 0 && kap == sk) mj[j] = tin;
        }
        if (kap == sk) {
            #pragma unroll
            for (int j = 0; j < 8; ++j) {
                f32x4 c = __builtin_bit_cast(f32x4, acc[si][j]);
                const int ng = n0 + wn + j * 16 + (lane & 15);
                #pragma unroll
                for (int r = 0; r < 4; ++r) {
                    float rst = (mj[j] > 1.0f) ? 1.0f : 0.0f;
                    mj[j] = __fsub_rn(__fadd_rn(__fmul_rn(0.9f, mj[j]), c[r]), rst);
                    So[(size_t)(seg * 4 + r) * N + ng] = (mj[j] > 1.0f) ? (signed char)1 : (signed char)0;
                }
            }
        }
    }
}

// ================= i8 GEMM B + fused LIF -> f32 output: block 128x128, wave 64x64 =====
__global__ __launch_bounds__(256, 2)
void snn_gemm_i8_n_lif(const signed char* __restrict__ A,
                       const signed char* __restrict__ Wq,
                       const float* __restrict__ bias,
                       float* __restrict__ Dout,        // [S, Bsz, N] f32 spikes
                       int M, int N, int K, int Bsz) {
    __shared__ __align__(16) char As[3 * 8192];
    __shared__ __align__(16) char Bs[3 * 8192];
    const int t    = threadIdx.x;
    const int wave = t >> 6;
    const int lane = t & 63;

    int m_idx, n_idx;
    {
        int gx = gridDim.x, gy = gridDim.y;
        int flat = blockIdx.y * gx + blockIdx.x;
        if ((gy & 7) == 0) {
            int x = flat & 7, local = flat >> 3, h = gy >> 3;
            m_idx = x * h + (local % h);
            n_idx = local / h;
        } else { m_idx = blockIdx.y; n_idx = blockIdx.x; }
    }
    const int m0 = m_idx * 128;
    const int n0 = n_idx * 128;
    const int wm = (wave & 1) * 64;
    const int wn = (wave >> 1) * 64;

    const int srow = lane >> 2;
    const int schk = ((lane & 3) + (lane >> 2) + (lane >> 4)) & 3;
    const int rho  = lane & 15;
    const int kap  = lane >> 4;
    const int foff = ((rho << 2) + ((kap - rho - (rho >> 2)) & 3)) * 16;   // bytes

    const int KT = K >> 6;
    const int NT = 3 * KT;
    const size_t PK = (size_t)N * K;

    size_t aOff[2], bOff[2];
    #pragma unroll
    for (int q = 0; q < 2; ++q) {
        aOff[q] = (size_t)(m0 + (wave * 2 + q) * 16 + srow) * K + schk * 16;
        bOff[q] = (size_t)(n0 + (wave * 2 + q) * 16 + srow) * K + schk * 16;
    }

    i32x4 acc[4][4] = {};
    i32x4 afA[4], afB[4], bLo[2], bHi[2];

    auto stageT = [&](int p, int kt, int bsel) {
        const int kk = kt << 6;
        char* as = As + bsel * 8192;
        char* bs = Bs + bsel * 8192;
        const signed char* Bw = Wq + (size_t)p * PK;
        #pragma unroll
        for (int q = 0; q < 2; ++q) {
            async16(A  + aOff[q] + kk, as + (wave * 2 + q) * 1024 + lane * 16);
            async16(Bw + bOff[q] + kk, bs + (wave * 2 + q) * 1024 + lane * 16);
        }
    };

    int sp = 0, skt = 2;
    int sbuf = 2, rbuf = 1;

    auto body = [&](int i, i32x4* afc, i32x4* afn) {
        if (i + 2 < NT) {
            stageT(sp, skt, sbuf);
            if (++skt == KT) { skt = 0; ++sp; }
            asm volatile("s_waitcnt vmcnt(4)" ::: "memory");
        } else {
            asm volatile("s_waitcnt vmcnt(0)" ::: "memory");
        }
        __builtin_amdgcn_s_barrier();
        const char* as = As + rbuf * 8192;
        const char* bs = Bs + rbuf * 8192;
        #pragma unroll
        for (int q = 0; q < 4; ++q)
            afn[q] = *(const i32x4*)&as[((wm >> 4) + q) * 1024 + foff];
        #pragma unroll
        for (int q = 0; q < 2; ++q)
            bLo[q] = *(const i32x4*)&bs[((wn >> 4) + q) * 1024 + foff];
        __builtin_amdgcn_sched_barrier(0);
        #pragma unroll
        for (int q = 0; q < 4; ++q)
            #pragma unroll
            for (int j = 0; j < 2; ++j)
                acc[q][2 + j] = __builtin_amdgcn_mfma_i32_16x16x64_i8(afc[q], bHi[j], acc[q][2 + j], 0, 0, 0);
        #pragma unroll
        for (int q = 0; q < 2; ++q)
            bHi[q] = *(const i32x4*)&bs[((wn >> 4) + 2 + q) * 1024 + foff];
        asm volatile("s_waitcnt lgkmcnt(0)" ::: "memory");
        __builtin_amdgcn_sched_barrier(0);
        if (((i + 1) & (KT - 1)) == 0) {
            #pragma unroll
            for (int q = 0; q < 4; ++q)
                #pragma unroll
                for (int j = 0; j < 4; ++j)
                    acc[q][j] = acc[q][j] * 256;
        }
        #pragma unroll
        for (int q = 0; q < 4; ++q)
            #pragma unroll
            for (int j = 0; j < 2; ++j)
                acc[q][j] = __builtin_amdgcn_mfma_i32_16x16x64_i8(afn[q], bLo[j], acc[q][j], 0, 0, 0);
        sbuf = (sbuf == 2) ? 0 : sbuf + 1;
        rbuf = (rbuf == 2) ? 0 : rbuf + 1;
    };

    stageT(0, 0, 0);
    stageT(0, 1, 1);
    asm volatile("s_waitcnt vmcnt(4)" ::: "memory");
    __builtin_amdgcn_s_barrier();
    {
        const char* as = As;
        const char* bs = Bs;
        #pragma unroll
        for (int q = 0; q < 4; ++q)
            afA[q] = *(const i32x4*)&as[((wm >> 4) + q) * 1024 + foff];
        #pragma unroll
        for (int q = 0; q < 2; ++q) {
            bLo[q] = *(const i32x4*)&bs[((wn >> 4) + q) * 1024 + foff];
            bHi[q] = *(const i32x4*)&bs[((wn >> 4) + 2 + q) * 1024 + foff];
        }
    }
    asm volatile("s_waitcnt lgkmcnt(0)" ::: "memory");
    __builtin_amdgcn_sched_barrier(0);
    #pragma unroll
    for (int q = 0; q < 4; ++q)
        #pragma unroll
        for (int j = 0; j < 2; ++j)
            acc[q][j] = __builtin_amdgcn_mfma_i32_16x16x64_i8(afA[q], bLo[j], acc[q][j], 0, 0, 0);

    for (int i = 0; i < NT - 2; i += 2) {
        body(i, afA, afB);
        body(i + 1, afB, afA);
    }
    body(NT - 2, afA, afB);
    #pragma unroll
    for (int q = 0; q < 4; ++q)
        #pragma unroll
        for (int j = 0; j < 2; ++j)
            acc[q][2 + j] = __builtin_amdgcn_mfma_i32_16x16x64_i8(afB[q], bHi[j], acc[q][2 + j], 0, 0, 0);

    // ---------- fused LIF epilogue -> f32 spikes [S, Bsz, N] ----------
    const float SCALE = 7.450580596923828e-9f;   // 2^-27
    float bb[4];
    #pragma unroll
    for (int j = 0; j < 4; ++j)
        bb[j] = bias[n0 + wn + j * 16 + (lane & 15)];
    #pragma unroll
    for (int i = 0; i < 4; ++i)
        #pragma unroll
        for (int j = 0; j < 4; ++j) {
            i32x4 v = acc[i][j];
            f32x4 c;
            #pragma unroll
            for (int r = 0; r < 4; ++r)
                c[r] = (float)v[r] * SCALE + bb[j];
            acc[i][j] = __builtin_bit_cast(i32x4, c);
        }
    float mj[4] = {0.f, 0.f, 0.f, 0.f};
    const int b_idx = (m0 + wm) >> 6;
    #pragma unroll
    for (int seg = 0; seg < 16; ++seg) {
        const int si = seg >> 2, sk = seg & 3;
        const int src = (lane & 15) | (((sk + 3) & 3) << 4);
        #pragma unroll
        for (int j = 0; j < 4; ++j) {
            float tin = __shfl(mj[j], src);
            if (seg > 0 && kap == sk) mj[j] = tin;
        }
        if (kap == sk) {
            #pragma unroll
            for (int j = 0; j < 4; ++j) {
                f32x4 c = __builtin_bit_cast(f32x4, acc[si][j]);
                const int ng = n0 + wn + j * 16 + (lane & 15);
                #pragma unroll
                for (int r = 0; r < 4; ++r) {
                    float rst = (mj[j] > 1.0f) ? 1.0f : 0.0f;
                    mj[j] = __fsub_rn(__fadd_rn(__fmul_rn(0.9f, mj[j]), c[r]), rst);
                    Dout[((size_t)(seg * 4 + r) * Bsz + b_idx) * N + ng] = (mj[j] > 1.0f) ? 1.0f : 0.0f;
                }
            }
        }
    }
}

// ========== GEMM0 bf16, per-part blocks, pipelined (triple-buffer, 1 barrier) ==========
// M=256, N=1024, K=512.  grid (8, 2, 3): blockIdx.z = part -> writes Cpart[part].
// Same staging geometry as the i8 kernels: 16-row x 64B groups (here 32 bf16/row).
__global__ __launch_bounds__(256, 2)
void snn_gemm0_bf16p(const __hip_bfloat16* __restrict__ A,     // r_bf [256, 512]
                     const __hip_bfloat16* __restrict__ Wp,    // 3 parts, each [1024, 512]
                     float* __restrict__ Cpart) {              // [3][256][1024]
    constexpr int M = 256, N = 1024, K = 512;
    constexpr int KT = K / 32;                                 // 16 tiles
    __shared__ __align__(16) char As[3 * 8192];
    __shared__ __align__(16) char Bs[3 * 8192];
    const int t    = threadIdx.x;
    const int wave = t >> 6;
    const int lane = t & 63;

    const int part = blockIdx.z;
    const __hip_bfloat16* Bw = Wp + (size_t)part * N * K;
    float* C = Cpart + (size_t)part * M * N;
    const int m0 = blockIdx.y * 128;
    const int n0 = blockIdx.x * 128;
    const int wm = (wave & 1) * 64;
    const int wn = (wave >> 1) * 64;

    const int srow = lane >> 2;
    const int schk = ((lane & 3) + (lane >> 2) + (lane >> 4)) & 3;
    const int rho  = lane & 15;
    const int kap  = lane >> 4;
    const int foff = ((rho << 2) + ((kap - rho - (rho >> 2)) & 3)) * 16;   // bytes

    size_t aOff[2], bOff[2];
    #pragma unroll
    for (int q = 0; q < 2; ++q) {
        aOff[q] = (size_t)(m0 + (wave * 2 + q) * 16 + srow) * K + schk * 8;   // bf16 elems
        bOff[q] = (size_t)(n0 + (wave * 2 + q) * 16 + srow) * K + schk * 8;
    }

    f32x4 acc[4][4] = {};
    bf16x8 afA[4], afB[4], bLo[2], bHi[2];

    auto stageT = [&](int kt, int bsel) {
        const int kk = kt << 5;                // *32 elements
        char* as = As + bsel * 8192;
        char* bs = Bs + bsel * 8192;
        #pragma unroll
        for (int q = 0; q < 2; ++q) {
            async16(A  + aOff[q] + kk, as + (wave * 2 + q) * 1024 + lane * 16);
            async16(Bw + bOff[q] + kk, bs + (wave * 2 + q) * 1024 + lane * 16);
        }
    };

    int skt = 2;
    int sbuf = 2, rbuf = 1;

    auto body = [&](int i, bf16x8* afc, bf16x8* afn) {
        if (i + 2 < KT) {
            stageT(skt, sbuf);
            ++skt;
            asm volatile("s_waitcnt vmcnt(4)" ::: "memory");
        } else {
            asm volatile("s_waitcnt vmcnt(0)" ::: "memory");
        }
        __builtin_amdgcn_s_barrier();
        const char* as = As + rbuf * 8192;
        const char* bs = Bs + rbuf * 8192;
        #pragma unroll
        for (int q = 0; q < 4; ++q)
            afn[q] = *(const bf16x8*)&as[((wm >> 4) + q) * 1024 + foff];
        #pragma unroll
        for (int q = 0; q < 2; ++q)
            bLo[q] = *(const bf16x8*)&bs[((wn >> 4) + q) * 1024 + foff];
        __builtin_amdgcn_sched_barrier(0);
        #pragma unroll
        for (int q = 0; q < 4; ++q)
            #pragma unroll
            for (int j = 0; j < 2; ++j)
                acc[q][2 + j] = __builtin_amdgcn_mfma_f32_16x16x32_bf16(afc[q], bHi[j], acc[q][2 + j], 0, 0, 0);
        #pragma unroll
        for (int q = 0; q < 2; ++q)
            bHi[q] = *(const bf16x8*)&bs[((wn >> 4) + 2 + q) * 1024 + foff];
        asm volatile("s_waitcnt lgkmcnt(0)" ::: "memory");
        __builtin_amdgcn_sched_barrier(0);
        #pragma unroll
        for (int q = 0; q < 4; ++q)
            #pragma unroll
            for (int j = 0; j < 2; ++j)
                acc[q][j] = __builtin_amdgcn_mfma_f32_16x16x32_bf16(afn[q], bLo[j], acc[q][j], 0, 0, 0);
        sbuf = (sbuf == 2) ? 0 : sbuf + 1;
        rbuf = (rbuf == 2) ? 0 : rbuf + 1;
    };

    stageT(0, 0);
    stageT(1, 1);
    asm volatile("s_waitcnt vmcnt(4)" ::: "memory");
    __builtin_amdgcn_s_barrier();
    {
        const char* as = As;
        const char* bs = Bs;
        #pragma unroll
        for (int q = 0; q < 4; ++q)
            afA[q] = *(const bf16x8*)&as[((wm >> 4) + q) * 1024 + foff];
        #pragma unroll
        for (int q = 0; q < 2; ++q) {
            bLo[q] = *(const bf16x8*)&bs[((wn >> 4) + q) * 1024 + foff];
            bHi[q] = *(const bf16x8*)&bs[((wn >> 4) + 2 + q) * 1024 + foff];
        }
    }
    asm volatile("s_waitcnt lgkmcnt(0)" ::: "memory");
    __builtin_amdgcn_sched_barrier(0);
    #pragma unroll
    for (int q = 0; q < 4; ++q)
        #pragma unroll
        for (int j = 0; j < 2; ++j)
            acc[q][j] = __builtin_amdgcn_mfma_f32_16x16x32_bf16(afA[q], bLo[j], acc[q][j], 0, 0, 0);

    for (int i = 0; i < KT - 2; i += 2) {
        body(i, afA, afB);
        body(i + 1, afB, afA);
    }
    body(KT - 2, afA, afB);
    #pragma unroll
    for (int q = 0; q < 4; ++q)
        #pragma unroll
        for (int j = 0; j < 2; ++j)
            acc[q][2 + j] = __builtin_amdgcn_mfma_f32_16x16x32_bf16(afB[q], bHi[j], acc[q][2 + j], 0, 0, 0);

    // epilogue: plain C write (bias added later in lif0)
    #pragma unroll
    for (int i = 0; i < 4; ++i) {
        int mg = m0 + wm + i * 16 + (lane >> 4) * 4;
        #pragma unroll
        for (int j = 0; j < 4; ++j) {
            int ng = n0 + wn + j * 16 + (lane & 15);
            #pragma unroll
            for (int r = 0; r < 4; ++r)
                C[(size_t)(mg + r) * N + ng] = acc[i][j][r];
        }
    }
}

// -------- LIF layer 0: sum 3 part-slabs + bias, scan, b-major i8 spike output --------
__global__ void snn_lif0_sum3(const float4* __restrict__ p, const float4* __restrict__ b4,
                              uchar4* __restrict__ spk) {
    constexpr int MN4 = 256 * 1024 / 4;   // 65536
    constexpr int H4  = 256;              // 1024/4
    int idx = blockIdx.x * blockDim.x + threadIdx.x;
    if (idx >= MN4) return;
    const int b  = idx >> 8;
    const int h4 = idx & 255;
    float4 h = p[idx], mm = p[idx + MN4], l = p[idx + 2 * MN4], bb = b4[h4];
    float4 c;
    c.x = __fadd_rn(__fadd_rn(__fadd_rn(h.x, mm.x), l.x), bb.x);
    c.y = __fadd_rn(__fadd_rn(__fadd_rn(h.y, mm.y), l.y), bb.y);
    c.z = __fadd_rn(__fadd_rn(__fadd_rn(h.z, mm.z), l.z), bb.z);
    c.w = __fadd_rn(__fadd_rn(__fadd_rn(h.w, mm.w), l.w), bb.w);
    uchar4* out = spk + (size_t)b * S_STEPS * H4 + h4;
    float m0 = 0.0f, m1 = 0.0f, m2 = 0.0f, m3 = 0.0f;
    for (int s = 0; s < S_STEPS; ++s) {
        float r0 = (m0 > 1.0f) ? 1.0f : 0.0f;
        float r1 = (m1 > 1.0f) ? 1.0f : 0.0f;
        float r2 = (m2 > 1.0f) ? 1.0f : 0.0f;
        float r3 = (m3 > 1.0f) ? 1.0f : 0.0f;
        m0 = __fsub_rn(__fadd_rn(__fmul_rn(0.9f, m0), c.x), r0);
        m1 = __fsub_rn(__fadd_rn(__fmul_rn(0.9f, m1), c.y), r1);
        m2 = __fsub_rn(__fadd_rn(__fmul_rn(0.9f, m2), c.z), r2);
        m3 = __fsub_rn(__fadd_rn(__fmul_rn(0.9f, m3), c.w), r3);
        uchar4 o;
        o.x = (m0 > 1.0f) ? 1 : 0;
        o.y = (m1 > 1.0f) ? 1 : 0;
        o.z = (m2 > 1.0f) ? 1 : 0;
        o.w = (m3 > 1.0f) ? 1 : 0;
        out[(size_t)s * H4] = o;
    }
}

extern "C" void kernel_launch(void* const* d_in, const int* in_sizes, int n_in,
                              void* d_out, int out_size, void* d_ws, size_t ws_size,
                              hipStream_t stream) {
    const float* x  = (const float*)d_in[0];
    const float* W0 = (const float*)d_in[1];
    const float* b0 = (const float*)d_in[2];
    const float* W1 = (const float*)d_in[3];
    const float* b1 = (const float*)d_in[4];
    const float* W2 = (const float*)d_in[5];
    const float* b2 = (const float*)d_in[6];

    const int B = 256, T = 128, F = 512, H1 = 1024, H2 = 1024, H3 = 512;
    const int SB = S_STEPS * B;            // 16384

    // ---- workspace carve-up, all 16B aligned ----
    char* w = (char*)d_ws;
    signed char*    spk0 = (signed char*)w;                 w += (size_t)SB * H1;       // 16.7 MB
    signed char*    spk1 = (signed char*)w;                 w += (size_t)SB * H2;       // 16.7 MB
    __hip_bfloat16* r_bf = (__hip_bfloat16*)w;              w += (size_t)B * F * 2;     // 256 KB
    float*          cur0p = (float*)w;                      w += (size_t)3 * B * H1 * 4; // 3 MB
    __hip_bfloat16* W0s  = (__hip_bfloat16*)w;              w += (size_t)3 * H1 * F * 2;
    signed char*    W1q  = (signed char*)w;                 w += (size_t)3 * H2 * H1;   // 3 MB
    signed char*    W2q  = (signed char*)w;                 w += (size_t)3 * H3 * H2;   // 1.5 MB

    // 1. merged prep: encoder (512 blocks) + W0 split (512) + W1/W2 quant (1536)
    snn_prep<<<dim3(2560), dim3(256), 0, stream>>>(
        (const float4*)x, (ushort4*)r_bf,
        (const float4*)W0, (ushort4*)W0s,
        (const float4*)W1, (const float4*)W2,
        (char4*)W1q, (char4*)W2q);

    // 2. GEMM0 per part, pipelined: Cpart[p] = r @ W0s[p]^T   [3][256][1024]
    snn_gemm0_bf16p<<<dim3(H1 / 128, B / 128, 3), dim3(256), 0, stream>>>(
        r_bf, W0s, cur0p);

    // 3. LIF layer 0: sum parts + bias, scan -> spk0 i8, b-major rows b*64+s
    snn_lif0_sum3<<<dim3(B * H1 / 4 / 256), dim3(256), 0, stream>>>(
        (const float4*)cur0p, (const float4*)b0, (uchar4*)spk0);

    // 4+5. cur1 = spk0 @ W1^T + b1, fused LIF -> spk1 i8 b-major [16384 x 1024, K=1024]
    snn_gemm_i8_w_lif<<<dim3(H2 / 256, SB / 128), dim3(256), 0, stream>>>(
        spk0, W1q, b1, spk1, SB, H2, H1);

    // 6+7. cur2 = spk1 @ W2^T + b2, fused LIF -> d_out f32 [S, B, H3]
    snn_gemm_i8_n_lif<<<dim3(H3 / 128, SB / 128), dim3(256), 0, stream>>>(
        spk1, W2q, b2, (float*)d_out, SB, H3, H2, B);
}